// Round 2
// baseline (18639.961 us; speedup 1.0000x reference)
//
#include <hip/hip_runtime.h>
#include <hip/hip_bf16.h>
#include <math.h>

// Dims
#define B_SZ   32
#define L_SEQ  2048
#define BL     (B_SZ * L_SEQ)        // 65536
#define D_MODEL 256
#define D_INNER 512
#define D_STATE 16
#define D_CONV  4
#define LN_EPS  1e-5f

// ---------------------------------------------------------------------------
// input projection: h[row, c] = b[c] + sum_k x[row,k]*W[c,k]   (K=6)
// ---------------------------------------------------------------------------
__global__ __launch_bounds__(256) void input_proj_kernel(
    const float* __restrict__ x, const float* __restrict__ W,
    const float* __restrict__ b, float* __restrict__ h)
{
    size_t row = blockIdx.x;
    int c = threadIdx.x;
    const float* xr = x + row * 6;
    const float* wr = W + c * 6;
    float acc = b[c];
#pragma unroll
    for (int k = 0; k < 6; k++) acc += xr[k] * wr[k];
    h[row * D_MODEL + c] = acc;
}

// ---------------------------------------------------------------------------
// fp32 tiled GEMM:  C[M,N] = A[M,K] @ W[N,K]^T  (+ epilogue), strided A/C
// EPI 0: none, EPI 1: softplus(acc + bias[n]), EPI 2: acc + res (res==C ok)
// tile 128x128, BK=16, 256 threads, 8x8 micro-tile
// ---------------------------------------------------------------------------
template <int EPI>
__global__ __launch_bounds__(256) void gemm_f32(
    const float* __restrict__ A, int lda,
    const float* __restrict__ W,
    const float* __restrict__ bias, const float* __restrict__ res,
    float* __restrict__ C, int ldc, int M, int N, int K)
{
    __shared__ __align__(16) float As[16][128];
    __shared__ __align__(16) float Ws[16][128];
    const int tid = threadIdx.x;
    const int m0 = blockIdx.y * 128;
    const int n0 = blockIdx.x * 128;
    const int tx = tid & 15, ty = tid >> 4;

    float acc[8][8];
#pragma unroll
    for (int i = 0; i < 8; i++)
#pragma unroll
        for (int j = 0; j < 8; j++) acc[i][j] = 0.f;

    for (int k0 = 0; k0 < K; k0 += 16) {
#pragma unroll
        for (int it = 0; it < 2; it++) {
            int f = tid + it * 256;          // 0..511
            int row = f >> 2, kq = f & 3;
            float4 va = *(const float4*)(A + (size_t)(m0 + row) * lda + k0 + kq * 4);
            As[kq * 4 + 0][row] = va.x; As[kq * 4 + 1][row] = va.y;
            As[kq * 4 + 2][row] = va.z; As[kq * 4 + 3][row] = va.w;
            float4 vw = *(const float4*)(W + (size_t)(n0 + row) * K + k0 + kq * 4);
            Ws[kq * 4 + 0][row] = vw.x; Ws[kq * 4 + 1][row] = vw.y;
            Ws[kq * 4 + 2][row] = vw.z; Ws[kq * 4 + 3][row] = vw.w;
        }
        __syncthreads();
#pragma unroll
        for (int k = 0; k < 16; k++) {
            float a[8], b8[8];
            *(float4*)(a)     = *(const float4*)&As[k][ty * 8];
            *(float4*)(a + 4) = *(const float4*)&As[k][ty * 8 + 4];
            *(float4*)(b8)     = *(const float4*)&Ws[k][tx * 8];
            *(float4*)(b8 + 4) = *(const float4*)&Ws[k][tx * 8 + 4];
#pragma unroll
            for (int i = 0; i < 8; i++)
#pragma unroll
                for (int j = 0; j < 8; j++) acc[i][j] += a[i] * b8[j];
        }
        __syncthreads();
    }

#pragma unroll
    for (int i = 0; i < 8; i++) {
        size_t m = (size_t)(m0 + ty * 8 + i);
#pragma unroll
        for (int j = 0; j < 8; j++) {
            int n = n0 + tx * 8 + j;
            float v = acc[i][j];
            if (EPI == 1) {
                v += bias[n];
                v = (v > 20.f) ? v : log1pf(expf(v));
            } else if (EPI == 2) {
                v += res[m * ldc + n];
            }
            C[m * ldc + n] = v;
        }
    }
}

// ---------------------------------------------------------------------------
// causal depthwise conv (k=4, left pad 3) + SiLU, over R rows (whole batches).
// xz: (R,1024), xp = cols 0..511.  xc out: (R,512)
// ---------------------------------------------------------------------------
__global__ __launch_bounds__(256) void conv_silu_kernel(
    const float* __restrict__ xz, const float* __restrict__ cw,
    const float* __restrict__ cb, float* __restrict__ xc)
{
    size_t idx = (size_t)blockIdx.x * 256 + threadIdx.x;  // over R*512
    int d = (int)(idx & 511);
    int row = (int)(idx >> 9);
    int t = row & (L_SEQ - 1);
    float4 w = *(const float4*)(cw + d * 4);
    float acc = cb[d];
    if (t >= 3) {
        const float* xp = xz + (size_t)row * 1024 + d;
        acc += xp[-3 * 1024] * w.x + xp[-2 * 1024] * w.y +
               xp[-1 * 1024] * w.z + xp[0] * w.w;
    } else {
        const float wj[4] = {w.x, w.y, w.z, w.w};
#pragma unroll
        for (int j = 0; j < 4; j++) {
            int tj = t + j - 3;
            if (tj >= 0) acc += xz[(size_t)(row + j - 3) * 1024 + d] * wj[j];
        }
    }
    float sig = 1.f / (1.f + __expf(-acc));
    xc[idx] = acc * sig;
}

// ---------------------------------------------------------------------------
// x_proj: bc[row, c] = sum_k xc[row,k]*Wx[c,k]   (N=32, K=512)
// ---------------------------------------------------------------------------
__global__ __launch_bounds__(256) void xproj_kernel(
    const float* __restrict__ xc, const float* __restrict__ Wx,
    float* __restrict__ bc)
{
    int tid = threadIdx.x;
    int c = tid & 31, rl = tid >> 5;
    size_t row = (size_t)blockIdx.x * 8 + rl;
    const float* xr = xc + row * 512;
    const float* wr = Wx + c * 512;
    float acc = 0.f;
#pragma unroll 4
    for (int k = 0; k < 512; k += 4) {
        float4 xv = *(const float4*)(xr + k);
        float4 wv = *(const float4*)(wr + k);
        acc += xv.x * wv.x + xv.y * wv.y + xv.z * wv.z + xv.w * wv.w;
    }
    bc[row * 32 + c] = acc;
}

// ---------------------------------------------------------------------------
// selective scan + gate, in-place over the dt (=xp) half of xzdt.
// xzdt: (R,1024) — cols 0..511 hold dt (in) -> gated y (out), 512..1023 hold z.
// lane = (chain d) * 16 + n.  16-lane groups share one (b,d) chain.
// h_n <- exp(A_n*dt)*h_n + dt*B_n*xc ;  y = sum_n h_n*C_n
// store: (y + xc*D) * silu(z)
// ---------------------------------------------------------------------------
__global__ __launch_bounds__(256) void scan_gate_kernel(
    float* xzdt,                       // (R,1024)
    const float* __restrict__ xc,      // (R,512)
    const float* __restrict__ bc,      // (R,32): B=0..15, C=16..31
    const float* __restrict__ A_log,   // (512,16) layer slice
    const float* __restrict__ Dp)      // (512)
{
    const int tid = threadIdx.x;
    const int chain = tid >> 4, n = tid & 15;
    const int b = blockIdx.x >> 5;                  // local batch in chunk
    const int d = ((blockIdx.x & 31) << 4) + chain;

    const float A = -__expf(A_log[d * 16 + n]);
    const float Dd = Dp[d];
    float h = 0.f;

    const size_t row0 = (size_t)b * L_SEQ;
    float* dtp = xzdt + row0 * 1024 + d;
    const float* zp = xzdt + row0 * 1024 + 512 + d;
    const float* xcp = xc + row0 * 512 + d;
    const float* bp = bc + row0 * 32 + n;

    float dtv = dtp[0], xcv = xcp[0], zv = zp[0], Bv = bp[0], Cv = bp[16];
    for (int t = 0; t < L_SEQ; t++) {
        float dtn = 0.f, xcn = 0.f, zn = 0.f, Bn = 0.f, Cn = 0.f;
        if (t < L_SEQ - 1) {   // prefetch next step (uniform branch)
            size_t o = (size_t)(t + 1);
            dtn = dtp[o * 1024]; xcn = xcp[o * 512]; zn = zp[o * 1024];
            Bn = bp[o * 32]; Cn = bp[o * 32 + 16];
        }
        float dA = __expf(A * dtv);
        h = dA * h + (dtv * Bv) * xcv;
        float pv = h * Cv;
        pv += __shfl_xor(pv, 8, 16);
        pv += __shfl_xor(pv, 4, 16);
        pv += __shfl_xor(pv, 2, 16);
        pv += __shfl_xor(pv, 1, 16);
        if (n == 0) {
            float sig = 1.f / (1.f + __expf(-zv));
            dtp[(size_t)t * 1024] = (pv + xcv * Dd) * (zv * sig);
        }
        dtv = dtn; xcv = xcn; zv = zn; Bv = Bn; Cv = Cn;
    }
}

// ---------------------------------------------------------------------------
// LayerNorm over 256 cols, in-place safe; one wave per row, 4 rows per block
// ---------------------------------------------------------------------------
__global__ __launch_bounds__(256) void ln256_kernel(
    const float* __restrict__ in, const float* __restrict__ g,
    const float* __restrict__ b, float* __restrict__ out)
{
    int wave = threadIdx.x >> 6, lane = threadIdx.x & 63;
    size_t row = (size_t)blockIdx.x * 4 + wave;
    const float* p = in + row * 256 + lane * 4;
    float4 v = *(const float4*)p;
    float s = v.x + v.y + v.z + v.w;
    float sq = v.x * v.x + v.y * v.y + v.z * v.z + v.w * v.w;
#pragma unroll
    for (int o = 32; o; o >>= 1) {
        s += __shfl_xor(s, o, 64);
        sq += __shfl_xor(sq, o, 64);
    }
    float m = s * (1.f / 256.f);
    float var = sq * (1.f / 256.f) - m * m;
    float rs = 1.f / sqrtf(var + LN_EPS);
    float4 gg = *(const float4*)(g + lane * 4);
    float4 bb = *(const float4*)(b + lane * 4);
    float4 o4;
    o4.x = (v.x - m) * rs * gg.x + bb.x;
    o4.y = (v.y - m) * rs * gg.y + bb.y;
    o4.z = (v.z - m) * rs * gg.z + bb.z;
    o4.w = (v.w - m) * rs * gg.w + bb.w;
    *(float4*)(out + row * 256 + lane * 4) = o4;
}

// ---------------------------------------------------------------------------
// head: tick-LN -> fusion (gelu, LN, linear) -> classifier.  1 block / batch row
// ---------------------------------------------------------------------------
__device__ __forceinline__ float gelu_exact(float x) {
    return 0.5f * x * (1.f + erff(x * 0.70710678118654752f));
}

__global__ __launch_bounds__(256) void head_kernel(
    const float* __restrict__ h, const float* __restrict__ sent,
    const float* __restrict__ ta,
    const float* __restrict__ eng, const float* __restrict__ enb,
    const float* __restrict__ w1, const float* __restrict__ b1,
    const float* __restrict__ lng, const float* __restrict__ lnb,
    const float* __restrict__ w2, const float* __restrict__ b2,
    const float* __restrict__ cw1, const float* __restrict__ cb1,
    const float* __restrict__ cw2, const float* __restrict__ cb2,
    const float* __restrict__ cw3, const float* __restrict__ cb3,
    float* __restrict__ out)
{
    __shared__ __align__(16) float comb[1036];
    __shared__ __align__(16) float fbuf[256];
    __shared__ float rs_[4], rq_[4];
    const int r = blockIdx.x, tid = threadIdx.x;

    // ---- tick = LN(h[:, L-1]) ----
    float v = h[((size_t)r * L_SEQ + (L_SEQ - 1)) * 256 + tid];
    float s = v, sq = v * v;
#pragma unroll
    for (int o = 32; o; o >>= 1) { s += __shfl_xor(s, o, 64); sq += __shfl_xor(sq, o, 64); }
    if ((tid & 63) == 0) { rs_[tid >> 6] = s; rq_[tid >> 6] = sq; }
    __syncthreads();
    s = rs_[0] + rs_[1] + rs_[2] + rs_[3];
    sq = rq_[0] + rq_[1] + rq_[2] + rq_[3];
    float m = s * (1.f / 256.f);
    float var = sq * (1.f / 256.f) - m * m;
    float rstd = 1.f / sqrtf(var + LN_EPS);
    comb[tid] = (v - m) * rstd * eng[tid] + enb[tid];
    comb[256 + tid] = sent[(size_t)r * 768 + tid];
    comb[512 + tid] = sent[(size_t)r * 768 + 256 + tid];
    comb[768 + tid] = sent[(size_t)r * 768 + 512 + tid];
    if (tid < 12) comb[1024 + tid] = ta[(size_t)r * 12 + tid];
    __syncthreads();

    // ---- f1 = gelu(comb @ w1^T + b1) ----
    float acc = b1[tid];
    {
        const float* wr = w1 + (size_t)tid * 1036;
        for (int k = 0; k < 1036; k += 4) {
            float4 wv = *(const float4*)(wr + k);
            float4 cv = *(const float4*)(comb + k);
            acc += wv.x * cv.x + wv.y * cv.y + wv.z * cv.z + wv.w * cv.w;
        }
    }
    float f1 = gelu_exact(acc);

    // ---- LN(f1) ----
    s = f1; sq = f1 * f1;
#pragma unroll
    for (int o = 32; o; o >>= 1) { s += __shfl_xor(s, o, 64); sq += __shfl_xor(sq, o, 64); }
    if ((tid & 63) == 0) { rs_[tid >> 6] = s; rq_[tid >> 6] = sq; }
    __syncthreads();
    s = rs_[0] + rs_[1] + rs_[2] + rs_[3];
    sq = rq_[0] + rq_[1] + rq_[2] + rq_[3];
    m = s * (1.f / 256.f);
    var = sq * (1.f / 256.f) - m * m;
    rstd = 1.f / sqrtf(var + LN_EPS);
    fbuf[tid] = (f1 - m) * rstd * lng[tid] + lnb[tid];
    __syncthreads();

    // ---- f2 = fbuf @ w2^T + b2 ----
    acc = b2[tid];
    {
        const float* wr = w2 + (size_t)tid * 256;
        for (int k = 0; k < 256; k += 4) {
            float4 wv = *(const float4*)(wr + k);
            float4 cv = *(const float4*)(fbuf + k);
            acc += wv.x * cv.x + wv.y * cv.y + wv.z * cv.z + wv.w * cv.w;
        }
    }
    __syncthreads();
    comb[tid] = acc;     // f2 lives in comb[0..255]
    __syncthreads();

    // ---- c1 = gelu(f2 @ cw1^T + cb1), 128 ----
    if (tid < 128) {
        float a = cb1[tid];
        const float* wr = cw1 + (size_t)tid * 256;
        for (int k = 0; k < 256; k += 4) {
            float4 wv = *(const float4*)(wr + k);
            float4 cv = *(const float4*)(comb + k);
            a += wv.x * cv.x + wv.y * cv.y + wv.z * cv.z + wv.w * cv.w;
        }
        fbuf[tid] = gelu_exact(a);
    }
    __syncthreads();

    // ---- c2 = gelu(c1 @ cw2^T + cb2), 64 ----
    float c2v = 0.f;
    if (tid < 64) {
        float a = cb2[tid];
        const float* wr = cw2 + (size_t)tid * 128;
        for (int k = 0; k < 128; k += 4) {
            float4 wv = *(const float4*)(wr + k);
            float4 cv = *(const float4*)(fbuf + k);
            a += wv.x * cv.x + wv.y * cv.y + wv.z * cv.z + wv.w * cv.w;
        }
        c2v = gelu_exact(a);
    }
    __syncthreads();
    if (tid < 64) comb[tid] = c2v;
    __syncthreads();

    // ---- logits ----
    if (tid < 3) {
        float a = cb3[tid];
        const float* wr = cw3 + (size_t)tid * 64;
        for (int k = 0; k < 64; k++) a += wr[k] * comb[k];
        out[(size_t)r * 3 + tid] = a;
    }
}

// ---------------------------------------------------------------------------
extern "C" void kernel_launch(void* const* d_in, const int* in_sizes, int n_in,
                              void* d_out, int out_size, void* d_ws, size_t ws_size,
                              hipStream_t stream) {
    const float* x    = (const float*)d_in[0];
    const float* sent = (const float*)d_in[1];
    const float* ta   = (const float*)d_in[2];
    const float* ipw  = (const float*)d_in[3];
    const float* ipb  = (const float*)d_in[4];
    const float* inw  = (const float*)d_in[5];
    const float* cw   = (const float*)d_in[6];
    const float* cb   = (const float*)d_in[7];
    const float* xpw  = (const float*)d_in[8];
    const float* dtw  = (const float*)d_in[9];
    const float* dtb  = (const float*)d_in[10];
    const float* alog = (const float*)d_in[11];
    const float* Dp   = (const float*)d_in[12];
    const float* opw  = (const float*)d_in[13];
    const float* lng  = (const float*)d_in[14];
    const float* lnb  = (const float*)d_in[15];
    const float* eng  = (const float*)d_in[16];
    const float* enb  = (const float*)d_in[17];
    const float* fw1  = (const float*)d_in[18];
    const float* fb1  = (const float*)d_in[19];
    const float* flg  = (const float*)d_in[20];
    const float* flb  = (const float*)d_in[21];
    const float* fw2  = (const float*)d_in[22];
    const float* fb2  = (const float*)d_in[23];
    const float* cw1  = (const float*)d_in[24];
    const float* cb1  = (const float*)d_in[25];
    const float* cw2  = (const float*)d_in[26];
    const float* cb2  = (const float*)d_in[27];
    const float* cw3  = (const float*)d_in[28];
    const float* cb3  = (const float*)d_in[29];
    float* out = (float*)d_out;

    // --- workspace budget: h (persistent, BL*256) + chunk temporaries.
    // Temporaries per row: xz 1024 (xp->dt->gated y in cols 0..511, z in 512..1023)
    //                    + xc 512 + bc 32 = 1568 floats.
    // Chunk over whole batches until it fits ws_size (deterministic per ws_size,
    // so graph capture sees the same launch sequence every call).
    int c = 1;
    while (c < 32 &&
           ((size_t)BL * 256 + ((size_t)BL / c) * 1568) * sizeof(float) > ws_size)
        c <<= 1;
    const size_t R = BL / c;        // rows per chunk (multiple of L_SEQ)
    const int nb = B_SZ / c;        // batches per chunk

    float* ws = (float*)d_ws;
    float* hbuf  = ws;                         // BL*256 (persistent)
    float* xzbuf = hbuf + (size_t)BL * 256;    // R*1024
    float* xcbuf = xzbuf + R * 1024;           // R*512
    float* bcbuf = xcbuf + R * 512;            // R*32

    input_proj_kernel<<<BL, 256, 0, stream>>>(x, ipw, ipb, hbuf);

    for (int l = 0; l < 4; l++) {
        const float* inw_l = inw + (size_t)l * 1024 * 256;
        const float* cw_l  = cw  + (size_t)l * 512 * 4;
        const float* cb_l  = cb  + (size_t)l * 512;
        const float* xpw_l = xpw + (size_t)l * 32 * 512;
        const float* dtw_l = dtw + (size_t)l * 512 * 512;
        const float* dtb_l = dtb + (size_t)l * 512;
        const float* al_l  = alog + (size_t)l * 512 * 16;
        const float* Dp_l  = Dp  + (size_t)l * 512;
        const float* opw_l = opw + (size_t)l * 256 * 512;
        const float* lng_l = lng + (size_t)l * 256;
        const float* lnb_l = lnb + (size_t)l * 256;

        for (int k = 0; k < c; k++) {
            float* hck = hbuf + (size_t)k * R * 256;

            // xz = h @ Wi^T            (R x 1024)
            gemm_f32<0><<<dim3(1024 / 128, R / 128), 256, 0, stream>>>(
                hck, 256, inw_l, nullptr, nullptr, xzbuf, 1024, (int)R, 1024, 256);
            // xc = silu(causal dwconv(xp) + cb)
            conv_silu_kernel<<<(unsigned)(R * 2), 256, 0, stream>>>(
                xzbuf, cw_l, cb_l, xcbuf);
            // dt = softplus(xc @ Wdt^T + bdt)  -> xz cols 0..511 (xp is dead)
            gemm_f32<1><<<dim3(512 / 128, R / 128), 256, 0, stream>>>(
                xcbuf, 512, dtw_l, dtb_l, nullptr, xzbuf, 1024, (int)R, 512, 512);
            // bc = xc @ Wx^T            (R x 32)
            xproj_kernel<<<(unsigned)(R / 8), 256, 0, stream>>>(xcbuf, xpw_l, bcbuf);
            // selective scan + gate, in-place over dt half
            scan_gate_kernel<<<(unsigned)(nb * 32), 256, 0, stream>>>(
                xzbuf, xcbuf, bcbuf, al_l, Dp_l);
            // h += y @ Wo^T  (in-place residual), then LN in-place
            gemm_f32<2><<<dim3(256 / 128, R / 128), 256, 0, stream>>>(
                xzbuf, 1024, opw_l, nullptr, hck, hck, 256, (int)R, 256, 512);
            ln256_kernel<<<(unsigned)(R / 4), 256, 0, stream>>>(
                hck, lng_l, lnb_l, hck);
        }
    }

    head_kernel<<<32, 256, 0, stream>>>(hbuf, sent, ta, eng, enb,
                                        fw1, fb1, flg, flb, fw2, fb2,
                                        cw1, cb1, cw2, cb2, cw3, cb3, out);
}

// Round 3
// 16217.751 us; speedup vs baseline: 1.1494x; 1.1494x over previous
//
#include <hip/hip_runtime.h>
#include <hip/hip_bf16.h>
#include <math.h>

// Dims
#define B_SZ   32
#define L_SEQ  2048
#define BL     (B_SZ * L_SEQ)        // 65536
#define D_MODEL 256
#define D_INNER 512
#define D_STATE 16
#define D_CONV  4
#define LN_EPS  1e-5f

// ---------------------------------------------------------------------------
// input projection: h[row, c] = b[c] + sum_k x[row,k]*W[c,k]   (K=6)
// ---------------------------------------------------------------------------
__global__ __launch_bounds__(256) void input_proj_kernel(
    const float* __restrict__ x, const float* __restrict__ W,
    const float* __restrict__ b, float* __restrict__ h)
{
    size_t row = blockIdx.x;
    int c = threadIdx.x;
    const float* xr = x + row * 6;
    const float* wr = W + c * 6;
    float acc = b[c];
#pragma unroll
    for (int k = 0; k < 6; k++) acc += xr[k] * wr[k];
    h[row * D_MODEL + c] = acc;
}

// ---------------------------------------------------------------------------
// fp32 tiled GEMM:  C[M,N] = A[M,K] @ W[N,K]^T  (+ epilogue), strided A/C
// EPI 0: none, EPI 1: softplus(acc + bias[n]), EPI 2: acc + res (res==C ok)
// tile 128x128, BK=16, 256 threads, 8x8 micro-tile
// ---------------------------------------------------------------------------
template <int EPI>
__global__ __launch_bounds__(256) void gemm_f32(
    const float* __restrict__ A, int lda,
    const float* __restrict__ W,
    const float* __restrict__ bias, const float* __restrict__ res,
    float* __restrict__ C, int ldc, int M, int N, int K)
{
    __shared__ __align__(16) float As[16][128];
    __shared__ __align__(16) float Ws[16][128];
    const int tid = threadIdx.x;
    const int m0 = blockIdx.y * 128;
    const int n0 = blockIdx.x * 128;
    const int tx = tid & 15, ty = tid >> 4;

    float acc[8][8];
#pragma unroll
    for (int i = 0; i < 8; i++)
#pragma unroll
        for (int j = 0; j < 8; j++) acc[i][j] = 0.f;

    for (int k0 = 0; k0 < K; k0 += 16) {
#pragma unroll
        for (int it = 0; it < 2; it++) {
            int f = tid + it * 256;          // 0..511
            int row = f >> 2, kq = f & 3;
            float4 va = *(const float4*)(A + (size_t)(m0 + row) * lda + k0 + kq * 4);
            As[kq * 4 + 0][row] = va.x; As[kq * 4 + 1][row] = va.y;
            As[kq * 4 + 2][row] = va.z; As[kq * 4 + 3][row] = va.w;
            float4 vw = *(const float4*)(W + (size_t)(n0 + row) * K + k0 + kq * 4);
            Ws[kq * 4 + 0][row] = vw.x; Ws[kq * 4 + 1][row] = vw.y;
            Ws[kq * 4 + 2][row] = vw.z; Ws[kq * 4 + 3][row] = vw.w;
        }
        __syncthreads();
#pragma unroll
        for (int k = 0; k < 16; k++) {
            float a[8], b8[8];
            *(float4*)(a)     = *(const float4*)&As[k][ty * 8];
            *(float4*)(a + 4) = *(const float4*)&As[k][ty * 8 + 4];
            *(float4*)(b8)     = *(const float4*)&Ws[k][tx * 8];
            *(float4*)(b8 + 4) = *(const float4*)&Ws[k][tx * 8 + 4];
#pragma unroll
            for (int i = 0; i < 8; i++)
#pragma unroll
                for (int j = 0; j < 8; j++) acc[i][j] += a[i] * b8[j];
        }
        __syncthreads();
    }

#pragma unroll
    for (int i = 0; i < 8; i++) {
        size_t m = (size_t)(m0 + ty * 8 + i);
#pragma unroll
        for (int j = 0; j < 8; j++) {
            int n = n0 + tx * 8 + j;
            float v = acc[i][j];
            if (EPI == 1) {
                v += bias[n];
                v = (v > 20.f) ? v : log1pf(expf(v));
            } else if (EPI == 2) {
                v += res[m * ldc + n];
            }
            C[m * ldc + n] = v;
        }
    }
}

// ---------------------------------------------------------------------------
// causal depthwise conv (k=4, left pad 3) + SiLU, over R rows (whole batches).
// xz: (R,1024), xp = cols 0..511.  xc out: (R,512)
// ---------------------------------------------------------------------------
__global__ __launch_bounds__(256) void conv_silu_kernel(
    const float* __restrict__ xz, const float* __restrict__ cw,
    const float* __restrict__ cb, float* __restrict__ xc)
{
    size_t idx = (size_t)blockIdx.x * 256 + threadIdx.x;  // over R*512
    int d = (int)(idx & 511);
    int row = (int)(idx >> 9);
    int t = row & (L_SEQ - 1);
    float4 w = *(const float4*)(cw + d * 4);
    float acc = cb[d];
    if (t >= 3) {
        const float* xp = xz + (size_t)row * 1024 + d;
        acc += xp[-3 * 1024] * w.x + xp[-2 * 1024] * w.y +
               xp[-1 * 1024] * w.z + xp[0] * w.w;
    } else {
        const float wj[4] = {w.x, w.y, w.z, w.w};
#pragma unroll
        for (int j = 0; j < 4; j++) {
            int tj = t + j - 3;
            if (tj >= 0) acc += xz[(size_t)(row + j - 3) * 1024 + d] * wj[j];
        }
    }
    float sig = 1.f / (1.f + __expf(-acc));
    xc[idx] = acc * sig;
}

// ---------------------------------------------------------------------------
// x_proj: bc[row, c] = sum_k xc[row,k]*Wx[c,k]   (N=32, K=512)
// ---------------------------------------------------------------------------
__global__ __launch_bounds__(256) void xproj_kernel(
    const float* __restrict__ xc, const float* __restrict__ Wx,
    float* __restrict__ bc)
{
    int tid = threadIdx.x;
    int c = tid & 31, rl = tid >> 5;
    size_t row = (size_t)blockIdx.x * 8 + rl;
    const float* xr = xc + row * 512;
    const float* wr = Wx + c * 512;
    float acc = 0.f;
#pragma unroll 4
    for (int k = 0; k < 512; k += 4) {
        float4 xv = *(const float4*)(xr + k);
        float4 wv = *(const float4*)(wr + k);
        acc += xv.x * wv.x + xv.y * wv.y + xv.z * wv.z + xv.w * wv.w;
    }
    bc[row * 32 + c] = acc;
}

// ---------------------------------------------------------------------------
// selective scan + gate, in-place over the dt (=xp) half of xzdt.
// xzdt: (R,1024) — cols 0..511 hold dt (in) -> gated y (out), 512..1023 hold z.
// lane = (chain d) * 16 + n.  16-lane groups share one (b,d) chain.
// h_n <- exp(A_n*dt)*h_n + dt*B_n*xc ;  y = sum_n h_n*C_n
// store: (y + xc*D) * silu(z)
// PF-deep register software pipeline: ~40 outstanding loads hide HBM latency
// (round 2 showed 1-deep prefetch => 212 GB/s, latency-bound, 675us/chunk).
// In-place hazard safe: write at t, reads at t+PF, same group owns column d.
// ---------------------------------------------------------------------------
#define PF 8
__global__ __launch_bounds__(256) void scan_gate_kernel(
    float* xzdt,                       // (R,1024)
    const float* __restrict__ xc,      // (R,512)
    const float* __restrict__ bc,      // (R,32): B=0..15, C=16..31
    const float* __restrict__ A_log,   // (512,16) layer slice
    const float* __restrict__ Dp)      // (512)
{
    const int tid = threadIdx.x;
    const int chain = tid >> 4, n = tid & 15;
    const int b = blockIdx.x >> 5;                  // local batch in chunk
    const int d = ((blockIdx.x & 31) << 4) + chain;

    const float A = -__expf(A_log[d * 16 + n]);
    const float Dd = Dp[d];
    float h = 0.f;

    const size_t row0 = (size_t)b * L_SEQ;
    float* dtp = xzdt + row0 * 1024 + d;
    const float* zp = xzdt + row0 * 1024 + 512 + d;
    const float* xcp = xc + row0 * 512 + d;
    const float* bp = bc + row0 * 32 + n;

    float dt_r[PF], xc_r[PF], z_r[PF], B_r[PF], C_r[PF];
#pragma unroll
    for (int j = 0; j < PF; j++) {
        dt_r[j] = dtp[(size_t)j * 1024];
        xc_r[j] = xcp[(size_t)j * 512];
        z_r[j]  = zp[(size_t)j * 1024];
        B_r[j]  = bp[(size_t)j * 32];
        C_r[j]  = bp[(size_t)j * 32 + 16];
    }

    for (int t0 = 0; t0 < L_SEQ; t0 += PF) {
#pragma unroll
        for (int j = 0; j < PF; j++) {
            const int t = t0 + j;
            const float dtv = dt_r[j], xcv = xc_r[j], zv = z_r[j];
            const float Bv = B_r[j], Cv = C_r[j];

            // refill slot j with step t+PF (clamped in-bounds; tail values unused)
            const size_t tn = (size_t)((t + PF < L_SEQ) ? (t + PF) : t);
            dt_r[j] = dtp[tn * 1024];
            xc_r[j] = xcp[tn * 512];
            z_r[j]  = zp[tn * 1024];
            B_r[j]  = bp[tn * 32];
            C_r[j]  = bp[tn * 32 + 16];

            const float dA = __expf(A * dtv);
            h = dA * h + (dtv * Bv) * xcv;
            float pv = h * Cv;
            pv += __shfl_xor(pv, 8, 16);
            pv += __shfl_xor(pv, 4, 16);
            pv += __shfl_xor(pv, 2, 16);
            pv += __shfl_xor(pv, 1, 16);
            if (n == 0) {
                float sig = 1.f / (1.f + __expf(-zv));
                dtp[(size_t)t * 1024] = (pv + xcv * Dd) * (zv * sig);
            }
        }
    }
}

// ---------------------------------------------------------------------------
// LayerNorm over 256 cols, in-place safe; one wave per row, 4 rows per block
// ---------------------------------------------------------------------------
__global__ __launch_bounds__(256) void ln256_kernel(
    const float* __restrict__ in, const float* __restrict__ g,
    const float* __restrict__ b, float* __restrict__ out)
{
    int wave = threadIdx.x >> 6, lane = threadIdx.x & 63;
    size_t row = (size_t)blockIdx.x * 4 + wave;
    const float* p = in + row * 256 + lane * 4;
    float4 v = *(const float4*)p;
    float s = v.x + v.y + v.z + v.w;
    float sq = v.x * v.x + v.y * v.y + v.z * v.z + v.w * v.w;
#pragma unroll
    for (int o = 32; o; o >>= 1) {
        s += __shfl_xor(s, o, 64);
        sq += __shfl_xor(sq, o, 64);
    }
    float m = s * (1.f / 256.f);
    float var = sq * (1.f / 256.f) - m * m;
    float rs = 1.f / sqrtf(var + LN_EPS);
    float4 gg = *(const float4*)(g + lane * 4);
    float4 bb = *(const float4*)(b + lane * 4);
    float4 o4;
    o4.x = (v.x - m) * rs * gg.x + bb.x;
    o4.y = (v.y - m) * rs * gg.y + bb.y;
    o4.z = (v.z - m) * rs * gg.z + bb.z;
    o4.w = (v.w - m) * rs * gg.w + bb.w;
    *(float4*)(out + row * 256 + lane * 4) = o4;
}

// ---------------------------------------------------------------------------
// head: tick-LN -> fusion (gelu, LN, linear) -> classifier.  1 block / batch row
// ---------------------------------------------------------------------------
__device__ __forceinline__ float gelu_exact(float x) {
    return 0.5f * x * (1.f + erff(x * 0.70710678118654752f));
}

__global__ __launch_bounds__(256) void head_kernel(
    const float* __restrict__ h, const float* __restrict__ sent,
    const float* __restrict__ ta,
    const float* __restrict__ eng, const float* __restrict__ enb,
    const float* __restrict__ w1, const float* __restrict__ b1,
    const float* __restrict__ lng, const float* __restrict__ lnb,
    const float* __restrict__ w2, const float* __restrict__ b2,
    const float* __restrict__ cw1, const float* __restrict__ cb1,
    const float* __restrict__ cw2, const float* __restrict__ cb2,
    const float* __restrict__ cw3, const float* __restrict__ cb3,
    float* __restrict__ out)
{
    __shared__ __align__(16) float comb[1036];
    __shared__ __align__(16) float fbuf[256];
    __shared__ float rs_[4], rq_[4];
    const int r = blockIdx.x, tid = threadIdx.x;

    // ---- tick = LN(h[:, L-1]) ----
    float v = h[((size_t)r * L_SEQ + (L_SEQ - 1)) * 256 + tid];
    float s = v, sq = v * v;
#pragma unroll
    for (int o = 32; o; o >>= 1) { s += __shfl_xor(s, o, 64); sq += __shfl_xor(sq, o, 64); }
    if ((tid & 63) == 0) { rs_[tid >> 6] = s; rq_[tid >> 6] = sq; }
    __syncthreads();
    s = rs_[0] + rs_[1] + rs_[2] + rs_[3];
    sq = rq_[0] + rq_[1] + rq_[2] + rq_[3];
    float m = s * (1.f / 256.f);
    float var = sq * (1.f / 256.f) - m * m;
    float rstd = 1.f / sqrtf(var + LN_EPS);
    comb[tid] = (v - m) * rstd * eng[tid] + enb[tid];
    comb[256 + tid] = sent[(size_t)r * 768 + tid];
    comb[512 + tid] = sent[(size_t)r * 768 + 256 + tid];
    comb[768 + tid] = sent[(size_t)r * 768 + 512 + tid];
    if (tid < 12) comb[1024 + tid] = ta[(size_t)r * 12 + tid];
    __syncthreads();

    // ---- f1 = gelu(comb @ w1^T + b1) ----
    float acc = b1[tid];
    {
        const float* wr = w1 + (size_t)tid * 1036;
        for (int k = 0; k < 1036; k += 4) {
            float4 wv = *(const float4*)(wr + k);
            float4 cv = *(const float4*)(comb + k);
            acc += wv.x * cv.x + wv.y * cv.y + wv.z * cv.z + wv.w * cv.w;
        }
    }
    float f1 = gelu_exact(acc);

    // ---- LN(f1) ----
    s = f1; sq = f1 * f1;
#pragma unroll
    for (int o = 32; o; o >>= 1) { s += __shfl_xor(s, o, 64); sq += __shfl_xor(sq, o, 64); }
    if ((tid & 63) == 0) { rs_[tid >> 6] = s; rq_[tid >> 6] = sq; }
    __syncthreads();
    s = rs_[0] + rs_[1] + rs_[2] + rs_[3];
    sq = rq_[0] + rq_[1] + rq_[2] + rq_[3];
    m = s * (1.f / 256.f);
    var = sq * (1.f / 256.f) - m * m;
    rstd = 1.f / sqrtf(var + LN_EPS);
    fbuf[tid] = (f1 - m) * rstd * lng[tid] + lnb[tid];
    __syncthreads();

    // ---- f2 = fbuf @ w2^T + b2 ----
    acc = b2[tid];
    {
        const float* wr = w2 + (size_t)tid * 256;
        for (int k = 0; k < 256; k += 4) {
            float4 wv = *(const float4*)(wr + k);
            float4 cv = *(const float4*)(fbuf + k);
            acc += wv.x * cv.x + wv.y * cv.y + wv.z * cv.z + wv.w * cv.w;
        }
    }
    __syncthreads();
    comb[tid] = acc;     // f2 lives in comb[0..255]
    __syncthreads();

    // ---- c1 = gelu(f2 @ cw1^T + cb1), 128 ----
    if (tid < 128) {
        float a = cb1[tid];
        const float* wr = cw1 + (size_t)tid * 256;
        for (int k = 0; k < 256; k += 4) {
            float4 wv = *(const float4*)(wr + k);
            float4 cv = *(const float4*)(comb + k);
            a += wv.x * cv.x + wv.y * cv.y + wv.z * cv.z + wv.w * cv.w;
        }
        fbuf[tid] = gelu_exact(a);
    }
    __syncthreads();

    // ---- c2 = gelu(c1 @ cw2^T + cb2), 64 ----
    float c2v = 0.f;
    if (tid < 64) {
        float a = cb2[tid];
        const float* wr = cw2 + (size_t)tid * 128;
        for (int k = 0; k < 128; k += 4) {
            float4 wv = *(const float4*)(wr + k);
            float4 cv = *(const float4*)(fbuf + k);
            a += wv.x * cv.x + wv.y * cv.y + wv.z * cv.z + wv.w * cv.w;
        }
        c2v = gelu_exact(a);
    }
    __syncthreads();
    if (tid < 64) comb[tid] = c2v;
    __syncthreads();

    // ---- logits ----
    if (tid < 3) {
        float a = cb3[tid];
        const float* wr = cw3 + (size_t)tid * 64;
        for (int k = 0; k < 64; k++) a += wr[k] * comb[k];
        out[(size_t)r * 3 + tid] = a;
    }
}

// ---------------------------------------------------------------------------
extern "C" void kernel_launch(void* const* d_in, const int* in_sizes, int n_in,
                              void* d_out, int out_size, void* d_ws, size_t ws_size,
                              hipStream_t stream) {
    const float* x    = (const float*)d_in[0];
    const float* sent = (const float*)d_in[1];
    const float* ta   = (const float*)d_in[2];
    const float* ipw  = (const float*)d_in[3];
    const float* ipb  = (const float*)d_in[4];
    const float* inw  = (const float*)d_in[5];
    const float* cw   = (const float*)d_in[6];
    const float* cb   = (const float*)d_in[7];
    const float* xpw  = (const float*)d_in[8];
    const float* dtw  = (const float*)d_in[9];
    const float* dtb  = (const float*)d_in[10];
    const float* alog = (const float*)d_in[11];
    const float* Dp   = (const float*)d_in[12];
    const float* opw  = (const float*)d_in[13];
    const float* lng  = (const float*)d_in[14];
    const float* lnb  = (const float*)d_in[15];
    const float* eng  = (const float*)d_in[16];
    const float* enb  = (const float*)d_in[17];
    const float* fw1  = (const float*)d_in[18];
    const float* fb1  = (const float*)d_in[19];
    const float* flg  = (const float*)d_in[20];
    const float* flb  = (const float*)d_in[21];
    const float* fw2  = (const float*)d_in[22];
    const float* fb2  = (const float*)d_in[23];
    const float* cw1  = (const float*)d_in[24];
    const float* cb1  = (const float*)d_in[25];
    const float* cw2  = (const float*)d_in[26];
    const float* cb2  = (const float*)d_in[27];
    const float* cw3  = (const float*)d_in[28];
    const float* cb3  = (const float*)d_in[29];
    float* out = (float*)d_out;

    // --- workspace budget: h (persistent, BL*256) + chunk temporaries.
    // Temporaries per row: xz 1024 (xp->dt->gated y in cols 0..511, z in 512..1023)
    //                    + xc 512 + bc 32 = 1568 floats.
    // Chunk over whole batches until it fits ws_size (deterministic per ws_size,
    // so graph capture sees the same launch sequence every call).
    int c = 1;
    while (c < 32 &&
           ((size_t)BL * 256 + ((size_t)BL / c) * 1568) * sizeof(float) > ws_size)
        c <<= 1;
    const size_t R = BL / c;        // rows per chunk (multiple of L_SEQ)
    const int nb = B_SZ / c;        // batches per chunk

    float* ws = (float*)d_ws;
    float* hbuf  = ws;                         // BL*256 (persistent)
    float* xzbuf = hbuf + (size_t)BL * 256;    // R*1024
    float* xcbuf = xzbuf + R * 1024;           // R*512
    float* bcbuf = xcbuf + R * 512;            // R*32

    input_proj_kernel<<<BL, 256, 0, stream>>>(x, ipw, ipb, hbuf);

    for (int l = 0; l < 4; l++) {
        const float* inw_l = inw + (size_t)l * 1024 * 256;
        const float* cw_l  = cw  + (size_t)l * 512 * 4;
        const float* cb_l  = cb  + (size_t)l * 512;
        const float* xpw_l = xpw + (size_t)l * 32 * 512;
        const float* dtw_l = dtw + (size_t)l * 512 * 512;
        const float* dtb_l = dtb + (size_t)l * 512;
        const float* al_l  = alog + (size_t)l * 512 * 16;
        const float* Dp_l  = Dp  + (size_t)l * 512;
        const float* opw_l = opw + (size_t)l * 256 * 512;
        const float* lng_l = lng + (size_t)l * 256;
        const float* lnb_l = lnb + (size_t)l * 256;

        for (int k = 0; k < c; k++) {
            float* hck = hbuf + (size_t)k * R * 256;

            // xz = h @ Wi^T            (R x 1024)
            gemm_f32<0><<<dim3(1024 / 128, R / 128), 256, 0, stream>>>(
                hck, 256, inw_l, nullptr, nullptr, xzbuf, 1024, (int)R, 1024, 256);
            // xc = silu(causal dwconv(xp) + cb)
            conv_silu_kernel<<<(unsigned)(R * 2), 256, 0, stream>>>(
                xzbuf, cw_l, cb_l, xcbuf);
            // dt = softplus(xc @ Wdt^T + bdt)  -> xz cols 0..511 (xp is dead)
            gemm_f32<1><<<dim3(512 / 128, R / 128), 256, 0, stream>>>(
                xcbuf, 512, dtw_l, dtb_l, nullptr, xzbuf, 1024, (int)R, 512, 512);
            // bc = xc @ Wx^T            (R x 32)
            xproj_kernel<<<(unsigned)(R / 8), 256, 0, stream>>>(xcbuf, xpw_l, bcbuf);
            // selective scan + gate, in-place over dt half
            scan_gate_kernel<<<(unsigned)(nb * 32), 256, 0, stream>>>(
                xzbuf, xcbuf, bcbuf, al_l, Dp_l);
            // h += y @ Wo^T  (in-place residual), then LN in-place
            gemm_f32<2><<<dim3(256 / 128, R / 128), 256, 0, stream>>>(
                xzbuf, 1024, opw_l, nullptr, hck, hck, 256, (int)R, 256, 512);
            ln256_kernel<<<(unsigned)(R / 4), 256, 0, stream>>>(
                hck, lng_l, lnb_l, hck);
        }
    }

    head_kernel<<<32, 256, 0, stream>>>(hbuf, sent, ta, eng, enb,
                                        fw1, fb1, flg, flb, fw2, fb2,
                                        cw1, cb1, cw2, cb2, cw3, cb3, out);
}

// Round 4
// 12840.414 us; speedup vs baseline: 1.4517x; 1.2630x over previous
//
#include <hip/hip_runtime.h>
#include <hip/hip_bf16.h>
#include <math.h>

// Dims
#define B_SZ   32
#define L_SEQ  2048
#define BL     (B_SZ * L_SEQ)        // 65536
#define D_MODEL 256
#define D_INNER 512
#define D_STATE 16
#define D_CONV  4
#define LN_EPS  1e-5f

// ---------------------------------------------------------------------------
// input projection: h[row, c] = b[c] + sum_k x[row,k]*W[c,k]   (K=6)
// ---------------------------------------------------------------------------
__global__ __launch_bounds__(256) void input_proj_kernel(
    const float* __restrict__ x, const float* __restrict__ W,
    const float* __restrict__ b, float* __restrict__ h)
{
    size_t row = blockIdx.x;
    int c = threadIdx.x;
    const float* xr = x + row * 6;
    const float* wr = W + c * 6;
    float acc = b[c];
#pragma unroll
    for (int k = 0; k < 6; k++) acc += xr[k] * wr[k];
    h[row * D_MODEL + c] = acc;
}

// ---------------------------------------------------------------------------
// fp32 tiled GEMM:  C[M,N] = A[M,K] @ W[N,K]^T  (+ epilogue), strided A/C
// EPI 0: none, EPI 1: softplus(acc + bias[n]), EPI 2: acc + res (res==C ok)
// tile 128x128, BK=16, 256 threads, 8x8 micro-tile
// ---------------------------------------------------------------------------
template <int EPI>
__global__ __launch_bounds__(256) void gemm_f32(
    const float* __restrict__ A, int lda,
    const float* __restrict__ W,
    const float* __restrict__ bias, const float* __restrict__ res,
    float* __restrict__ C, int ldc, int M, int N, int K)
{
    __shared__ __align__(16) float As[16][128];
    __shared__ __align__(16) float Ws[16][128];
    const int tid = threadIdx.x;
    const int m0 = blockIdx.y * 128;
    const int n0 = blockIdx.x * 128;
    const int tx = tid & 15, ty = tid >> 4;

    float acc[8][8];
#pragma unroll
    for (int i = 0; i < 8; i++)
#pragma unroll
        for (int j = 0; j < 8; j++) acc[i][j] = 0.f;

    for (int k0 = 0; k0 < K; k0 += 16) {
#pragma unroll
        for (int it = 0; it < 2; it++) {
            int f = tid + it * 256;          // 0..511
            int row = f >> 2, kq = f & 3;
            float4 va = *(const float4*)(A + (size_t)(m0 + row) * lda + k0 + kq * 4);
            As[kq * 4 + 0][row] = va.x; As[kq * 4 + 1][row] = va.y;
            As[kq * 4 + 2][row] = va.z; As[kq * 4 + 3][row] = va.w;
            float4 vw = *(const float4*)(W + (size_t)(n0 + row) * K + k0 + kq * 4);
            Ws[kq * 4 + 0][row] = vw.x; Ws[kq * 4 + 1][row] = vw.y;
            Ws[kq * 4 + 2][row] = vw.z; Ws[kq * 4 + 3][row] = vw.w;
        }
        __syncthreads();
#pragma unroll
        for (int k = 0; k < 16; k++) {
            float a[8], b8[8];
            *(float4*)(a)     = *(const float4*)&As[k][ty * 8];
            *(float4*)(a + 4) = *(const float4*)&As[k][ty * 8 + 4];
            *(float4*)(b8)     = *(const float4*)&Ws[k][tx * 8];
            *(float4*)(b8 + 4) = *(const float4*)&Ws[k][tx * 8 + 4];
#pragma unroll
            for (int i = 0; i < 8; i++)
#pragma unroll
                for (int j = 0; j < 8; j++) acc[i][j] += a[i] * b8[j];
        }
        __syncthreads();
    }

#pragma unroll
    for (int i = 0; i < 8; i++) {
        size_t m = (size_t)(m0 + ty * 8 + i);
#pragma unroll
        for (int j = 0; j < 8; j++) {
            int n = n0 + tx * 8 + j;
            float v = acc[i][j];
            if (EPI == 1) {
                v += bias[n];
                v = (v > 20.f) ? v : log1pf(expf(v));
            } else if (EPI == 2) {
                v += res[m * ldc + n];
            }
            C[m * ldc + n] = v;
        }
    }
}

// ---------------------------------------------------------------------------
// causal depthwise conv (k=4, left pad 3) + SiLU, over R rows (whole batches).
// xz: (R,1024), xp = cols 0..511.  xc out: (R,512)
// ---------------------------------------------------------------------------
__global__ __launch_bounds__(256) void conv_silu_kernel(
    const float* __restrict__ xz, const float* __restrict__ cw,
    const float* __restrict__ cb, float* __restrict__ xc)
{
    size_t idx = (size_t)blockIdx.x * 256 + threadIdx.x;  // over R*512
    int d = (int)(idx & 511);
    int row = (int)(idx >> 9);
    int t = row & (L_SEQ - 1);
    float4 w = *(const float4*)(cw + d * 4);
    float acc = cb[d];
    if (t >= 3) {
        const float* xp = xz + (size_t)row * 1024 + d;
        acc += xp[-3 * 1024] * w.x + xp[-2 * 1024] * w.y +
               xp[-1 * 1024] * w.z + xp[0] * w.w;
    } else {
        const float wj[4] = {w.x, w.y, w.z, w.w};
#pragma unroll
        for (int j = 0; j < 4; j++) {
            int tj = t + j - 3;
            if (tj >= 0) acc += xz[(size_t)(row + j - 3) * 1024 + d] * wj[j];
        }
    }
    float sig = 1.f / (1.f + __expf(-acc));
    xc[idx] = acc * sig;
}

// ---------------------------------------------------------------------------
// x_proj: bc[row, c] = sum_k xc[row,k]*Wx[c,k]   (N=32, K=512)
// ---------------------------------------------------------------------------
__global__ __launch_bounds__(256) void xproj_kernel(
    const float* __restrict__ xc, const float* __restrict__ Wx,
    float* __restrict__ bc)
{
    int tid = threadIdx.x;
    int c = tid & 31, rl = tid >> 5;
    size_t row = (size_t)blockIdx.x * 8 + rl;
    const float* xr = xc + row * 512;
    const float* wr = Wx + c * 512;
    float acc = 0.f;
#pragma unroll 4
    for (int k = 0; k < 512; k += 4) {
        float4 xv = *(const float4*)(xr + k);
        float4 wv = *(const float4*)(wr + k);
        acc += xv.x * wv.x + xv.y * wv.y + xv.z * wv.z + xv.w * wv.w;
    }
    bc[row * 32 + c] = acc;
}

// ---------------------------------------------------------------------------
// selective scan + gate, in-place over the dt (=xp) half of xzdt.
// xzdt: (R,1024) — cols 0..511 hold dt (in) -> gated y (out), 512..1023 hold z.
// lane = (chain d) * 16 + n.  16-lane groups share one (b,d) chain.
// h_n <- exp(A_n*dt)*h_n + dt*B_n*xc ;  y = sum_n h_n*C_n
// store: (y + xc*D) * silu(z)
//
// Round-4 restructure (round 3: 531us, VALUBusy 26%, 1 wave/SIMD — the 4-deep
// per-step shfl chain and short prefetch gap expose full latency):
//   process G=8 steps per stage, 2 register banks (prefetch 2 groups ahead):
//     consume:   dA[j]=exp(A*dt), u[j]=dt*B*xc   (parallel, 8-wide ILP)
//     refill:    issue next group's 40 loads (gap = 2 groups of compute)
//     recurrence: h=fma(dA,h,u); pv[j]=h*C[j]    (only true serial part)
//     reduction: 8 independent 4-deep shfl chains, latencies overlap
// Arithmetic identical to round-3 kernel (absmax 0.0).
// In-place hazard safe: writes at t, reads at t+16, same group owns column d.
// ---------------------------------------------------------------------------
#define G 8
__global__ __launch_bounds__(256) void scan_gate_kernel(
    float* xzdt,                       // (R,1024)
    const float* __restrict__ xc,      // (R,512)
    const float* __restrict__ bc,      // (R,32): B=0..15, C=16..31
    const float* __restrict__ A_log,   // (512,16) layer slice
    const float* __restrict__ Dp)      // (512)
{
    const int tid = threadIdx.x;
    const int chain = tid >> 4, n = tid & 15;
    const int b = blockIdx.x >> 5;                  // local batch in chunk
    const int d = ((blockIdx.x & 31) << 4) + chain;

    const float A = -__expf(A_log[d * 16 + n]);
    const float Dd = Dp[d];
    float h = 0.f;

    const size_t row0 = (size_t)b * L_SEQ;
    float* dtp = xzdt + row0 * 1024 + d;
    const float* zp = xzdt + row0 * 1024 + 512 + d;
    const float* xcp = xc + row0 * 512 + d;
    const float* bp = bc + row0 * 32 + n;

    float dtb_[2][G], xcb_[2][G], zb_[2][G], Bb_[2][G], Cb_[2][G];
#pragma unroll
    for (int hf = 0; hf < 2; hf++)
#pragma unroll
        for (int j = 0; j < G; j++) {
            const size_t t = (size_t)(hf * G + j);
            dtb_[hf][j] = dtp[t * 1024];
            xcb_[hf][j] = xcp[t * 512];
            zb_[hf][j]  = zp[t * 1024];
            Bb_[hf][j]  = bp[t * 32];
            Cb_[hf][j]  = bp[t * 32 + 16];
        }

    for (int t0 = 0; t0 < L_SEQ; t0 += 2 * G) {
#pragma unroll
        for (int hf = 0; hf < 2; hf++) {
            const int tb = t0 + hf * G;

            // ---- consume bank into independent temporaries (8-wide ILP)
            float dA[G], u[G], zl[G], Cl[G], xd[G];
#pragma unroll
            for (int j = 0; j < G; j++) {
                const float dtv = dtb_[hf][j], xcv = xcb_[hf][j];
                dA[j] = __expf(A * dtv);
                u[j]  = (dtv * Bb_[hf][j]) * xcv;
                xd[j] = xcv * Dd;
                zl[j] = zb_[hf][j];
                Cl[j] = Cb_[hf][j];
            }

            // ---- refill bank with steps tb+16 .. tb+23 (clamped; tail unused)
#pragma unroll
            for (int j = 0; j < G; j++) {
                const int tf = tb + 2 * G + j;
                const size_t tn = (size_t)((tf < L_SEQ) ? tf : tb + j);
                dtb_[hf][j] = dtp[tn * 1024];
                xcb_[hf][j] = xcp[tn * 512];
                zb_[hf][j]  = zp[tn * 1024];
                Bb_[hf][j]  = bp[tn * 32];
                Cb_[hf][j]  = bp[tn * 32 + 16];
            }

            // ---- serial recurrence (the only true dependency chain)
            float pv[G];
#pragma unroll
            for (int j = 0; j < G; j++) {
                h = fmaf(dA[j], h, u[j]);
                pv[j] = h * Cl[j];
            }

            // ---- batched reduction: 8 independent 4-deep shfl chains
#pragma unroll
            for (int j = 0; j < G; j++) pv[j] += __shfl_xor(pv[j], 8, 16);
#pragma unroll
            for (int j = 0; j < G; j++) pv[j] += __shfl_xor(pv[j], 4, 16);
#pragma unroll
            for (int j = 0; j < G; j++) pv[j] += __shfl_xor(pv[j], 2, 16);
#pragma unroll
            for (int j = 0; j < G; j++) pv[j] += __shfl_xor(pv[j], 1, 16);

            // ---- gate + store (lane n==0 owns column d's output)
            if (n == 0) {
#pragma unroll
                for (int j = 0; j < G; j++) {
                    const float zv = zl[j];
                    const float sig = 1.f / (1.f + __expf(-zv));
                    dtp[(size_t)(tb + j) * 1024] = (pv[j] + xd[j]) * (zv * sig);
                }
            }
        }
    }
}

// ---------------------------------------------------------------------------
// LayerNorm over 256 cols, in-place safe; one wave per row, 4 rows per block
// ---------------------------------------------------------------------------
__global__ __launch_bounds__(256) void ln256_kernel(
    const float* __restrict__ in, const float* __restrict__ g,
    const float* __restrict__ b, float* __restrict__ out)
{
    int wave = threadIdx.x >> 6, lane = threadIdx.x & 63;
    size_t row = (size_t)blockIdx.x * 4 + wave;
    const float* p = in + row * 256 + lane * 4;
    float4 v = *(const float4*)p;
    float s = v.x + v.y + v.z + v.w;
    float sq = v.x * v.x + v.y * v.y + v.z * v.z + v.w * v.w;
#pragma unroll
    for (int o = 32; o; o >>= 1) {
        s += __shfl_xor(s, o, 64);
        sq += __shfl_xor(sq, o, 64);
    }
    float m = s * (1.f / 256.f);
    float var = sq * (1.f / 256.f) - m * m;
    float rs = 1.f / sqrtf(var + LN_EPS);
    float4 gg = *(const float4*)(g + lane * 4);
    float4 bb = *(const float4*)(b + lane * 4);
    float4 o4;
    o4.x = (v.x - m) * rs * gg.x + bb.x;
    o4.y = (v.y - m) * rs * gg.y + bb.y;
    o4.z = (v.z - m) * rs * gg.z + bb.z;
    o4.w = (v.w - m) * rs * gg.w + bb.w;
    *(float4*)(out + row * 256 + lane * 4) = o4;
}

// ---------------------------------------------------------------------------
// head: tick-LN -> fusion (gelu, LN, linear) -> classifier.  1 block / batch row
// ---------------------------------------------------------------------------
__device__ __forceinline__ float gelu_exact(float x) {
    return 0.5f * x * (1.f + erff(x * 0.70710678118654752f));
}

__global__ __launch_bounds__(256) void head_kernel(
    const float* __restrict__ h, const float* __restrict__ sent,
    const float* __restrict__ ta,
    const float* __restrict__ eng, const float* __restrict__ enb,
    const float* __restrict__ w1, const float* __restrict__ b1,
    const float* __restrict__ lng, const float* __restrict__ lnb,
    const float* __restrict__ w2, const float* __restrict__ b2,
    const float* __restrict__ cw1, const float* __restrict__ cb1,
    const float* __restrict__ cw2, const float* __restrict__ cb2,
    const float* __restrict__ cw3, const float* __restrict__ cb3,
    float* __restrict__ out)
{
    __shared__ __align__(16) float comb[1036];
    __shared__ __align__(16) float fbuf[256];
    __shared__ float rs_[4], rq_[4];
    const int r = blockIdx.x, tid = threadIdx.x;

    // ---- tick = LN(h[:, L-1]) ----
    float v = h[((size_t)r * L_SEQ + (L_SEQ - 1)) * 256 + tid];
    float s = v, sq = v * v;
#pragma unroll
    for (int o = 32; o; o >>= 1) { s += __shfl_xor(s, o, 64); sq += __shfl_xor(sq, o, 64); }
    if ((tid & 63) == 0) { rs_[tid >> 6] = s; rq_[tid >> 6] = sq; }
    __syncthreads();
    s = rs_[0] + rs_[1] + rs_[2] + rs_[3];
    sq = rq_[0] + rq_[1] + rq_[2] + rq_[3];
    float m = s * (1.f / 256.f);
    float var = sq * (1.f / 256.f) - m * m;
    float rstd = 1.f / sqrtf(var + LN_EPS);
    comb[tid] = (v - m) * rstd * eng[tid] + enb[tid];
    comb[256 + tid] = sent[(size_t)r * 768 + tid];
    comb[512 + tid] = sent[(size_t)r * 768 + 256 + tid];
    comb[768 + tid] = sent[(size_t)r * 768 + 512 + tid];
    if (tid < 12) comb[1024 + tid] = ta[(size_t)r * 12 + tid];
    __syncthreads();

    // ---- f1 = gelu(comb @ w1^T + b1) ----
    float acc = b1[tid];
    {
        const float* wr = w1 + (size_t)tid * 1036;
        for (int k = 0; k < 1036; k += 4) {
            float4 wv = *(const float4*)(wr + k);
            float4 cv = *(const float4*)(comb + k);
            acc += wv.x * cv.x + wv.y * cv.y + wv.z * cv.z + wv.w * cv.w;
        }
    }
    float f1 = gelu_exact(acc);

    // ---- LN(f1) ----
    s = f1; sq = f1 * f1;
#pragma unroll
    for (int o = 32; o; o >>= 1) { s += __shfl_xor(s, o, 64); sq += __shfl_xor(sq, o, 64); }
    if ((tid & 63) == 0) { rs_[tid >> 6] = s; rq_[tid >> 6] = sq; }
    __syncthreads();
    s = rs_[0] + rs_[1] + rs_[2] + rs_[3];
    sq = rq_[0] + rq_[1] + rq_[2] + rq_[3];
    m = s * (1.f / 256.f);
    var = sq * (1.f / 256.f) - m * m;
    rstd = 1.f / sqrtf(var + LN_EPS);
    fbuf[tid] = (f1 - m) * rstd * lng[tid] + lnb[tid];
    __syncthreads();

    // ---- f2 = fbuf @ w2^T + b2 ----
    acc = b2[tid];
    {
        const float* wr = w2 + (size_t)tid * 256;
        for (int k = 0; k < 256; k += 4) {
            float4 wv = *(const float4*)(wr + k);
            float4 cv = *(const float4*)(fbuf + k);
            acc += wv.x * cv.x + wv.y * cv.y + wv.z * cv.z + wv.w * cv.w;
        }
    }
    __syncthreads();
    comb[tid] = acc;     // f2 lives in comb[0..255]
    __syncthreads();

    // ---- c1 = gelu(f2 @ cw1^T + cb1), 128 ----
    if (tid < 128) {
        float a = cb1[tid];
        const float* wr = cw1 + (size_t)tid * 256;
        for (int k = 0; k < 256; k += 4) {
            float4 wv = *(const float4*)(wr + k);
            float4 cv = *(const float4*)(comb + k);
            a += wv.x * cv.x + wv.y * cv.y + wv.z * cv.z + wv.w * cv.w;
        }
        fbuf[tid] = gelu_exact(a);
    }
    __syncthreads();

    // ---- c2 = gelu(c1 @ cw2^T + cb2), 64 ----
    float c2v = 0.f;
    if (tid < 64) {
        float a = cb2[tid];
        const float* wr = cw2 + (size_t)tid * 128;
        for (int k = 0; k < 128; k += 4) {
            float4 wv = *(const float4*)(wr + k);
            float4 cv = *(const float4*)(fbuf + k);
            a += wv.x * cv.x + wv.y * cv.y + wv.z * cv.z + wv.w * cv.w;
        }
        c2v = gelu_exact(a);
    }
    __syncthreads();
    if (tid < 64) comb[tid] = c2v;
    __syncthreads();

    // ---- logits ----
    if (tid < 3) {
        float a = cb3[tid];
        const float* wr = cw3 + (size_t)tid * 64;
        for (int k = 0; k < 64; k++) a += wr[k] * comb[k];
        out[(size_t)r * 3 + tid] = a;
    }
}

// ---------------------------------------------------------------------------
extern "C" void kernel_launch(void* const* d_in, const int* in_sizes, int n_in,
                              void* d_out, int out_size, void* d_ws, size_t ws_size,
                              hipStream_t stream) {
    const float* x    = (const float*)d_in[0];
    const float* sent = (const float*)d_in[1];
    const float* ta   = (const float*)d_in[2];
    const float* ipw  = (const float*)d_in[3];
    const float* ipb  = (const float*)d_in[4];
    const float* inw  = (const float*)d_in[5];
    const float* cw   = (const float*)d_in[6];
    const float* cb   = (const float*)d_in[7];
    const float* xpw  = (const float*)d_in[8];
    const float* dtw  = (const float*)d_in[9];
    const float* dtb  = (const float*)d_in[10];
    const float* alog = (const float*)d_in[11];
    const float* Dp   = (const float*)d_in[12];
    const float* opw  = (const float*)d_in[13];
    const float* lng  = (const float*)d_in[14];
    const float* lnb  = (const float*)d_in[15];
    const float* eng  = (const float*)d_in[16];
    const float* enb  = (const float*)d_in[17];
    const float* fw1  = (const float*)d_in[18];
    const float* fb1  = (const float*)d_in[19];
    const float* flg  = (const float*)d_in[20];
    const float* flb  = (const float*)d_in[21];
    const float* fw2  = (const float*)d_in[22];
    const float* fb2  = (const float*)d_in[23];
    const float* cw1  = (const float*)d_in[24];
    const float* cb1  = (const float*)d_in[25];
    const float* cw2  = (const float*)d_in[26];
    const float* cb2  = (const float*)d_in[27];
    const float* cw3  = (const float*)d_in[28];
    const float* cb3  = (const float*)d_in[29];
    float* out = (float*)d_out;

    // --- workspace budget: h (persistent, BL*256) + chunk temporaries.
    // Temporaries per row: xz 1024 (xp->dt->gated y in cols 0..511, z in 512..1023)
    //                    + xc 512 + bc 32 = 1568 floats.
    int c = 1;
    while (c < 32 &&
           ((size_t)BL * 256 + ((size_t)BL / c) * 1568) * sizeof(float) > ws_size)
        c <<= 1;
    const size_t R = BL / c;        // rows per chunk (multiple of L_SEQ)
    const int nb = B_SZ / c;        // batches per chunk

    float* ws = (float*)d_ws;
    float* hbuf  = ws;                         // BL*256 (persistent)
    float* xzbuf = hbuf + (size_t)BL * 256;    // R*1024
    float* xcbuf = xzbuf + R * 1024;           // R*512
    float* bcbuf = xcbuf + R * 512;            // R*32

    input_proj_kernel<<<BL, 256, 0, stream>>>(x, ipw, ipb, hbuf);

    for (int l = 0; l < 4; l++) {
        const float* inw_l = inw + (size_t)l * 1024 * 256;
        const float* cw_l  = cw  + (size_t)l * 512 * 4;
        const float* cb_l  = cb  + (size_t)l * 512;
        const float* xpw_l = xpw + (size_t)l * 32 * 512;
        const float* dtw_l = dtw + (size_t)l * 512 * 512;
        const float* dtb_l = dtb + (size_t)l * 512;
        const float* al_l  = alog + (size_t)l * 512 * 16;
        const float* Dp_l  = Dp  + (size_t)l * 512;
        const float* opw_l = opw + (size_t)l * 256 * 512;
        const float* lng_l = lng + (size_t)l * 256;
        const float* lnb_l = lnb + (size_t)l * 256;

        for (int k = 0; k < c; k++) {
            float* hck = hbuf + (size_t)k * R * 256;

            // xz = h @ Wi^T            (R x 1024)
            gemm_f32<0><<<dim3(1024 / 128, R / 128), 256, 0, stream>>>(
                hck, 256, inw_l, nullptr, nullptr, xzbuf, 1024, (int)R, 1024, 256);
            // xc = silu(causal dwconv(xp) + cb)
            conv_silu_kernel<<<(unsigned)(R * 2), 256, 0, stream>>>(
                xzbuf, cw_l, cb_l, xcbuf);
            // dt = softplus(xc @ Wdt^T + bdt)  -> xz cols 0..511 (xp is dead)
            gemm_f32<1><<<dim3(512 / 128, R / 128), 256, 0, stream>>>(
                xcbuf, 512, dtw_l, dtb_l, nullptr, xzbuf, 1024, (int)R, 512, 512);
            // bc = xc @ Wx^T            (R x 32)
            xproj_kernel<<<(unsigned)(R / 8), 256, 0, stream>>>(xcbuf, xpw_l, bcbuf);
            // selective scan + gate, in-place over dt half
            scan_gate_kernel<<<(unsigned)(nb * 32), 256, 0, stream>>>(
                xzbuf, xcbuf, bcbuf, al_l, Dp_l);
            // h += y @ Wo^T  (in-place residual), then LN in-place
            gemm_f32<2><<<dim3(256 / 128, R / 128), 256, 0, stream>>>(
                xzbuf, 1024, opw_l, nullptr, hck, hck, 256, (int)R, 256, 512);
            ln256_kernel<<<(unsigned)(R / 4), 256, 0, stream>>>(
                hck, lng_l, lnb_l, hck);
        }
    }

    head_kernel<<<32, 256, 0, stream>>>(hbuf, sent, ta, eng, enb,
                                        fw1, fb1, flg, flb, fw2, fb2,
                                        cw1, cb1, cw2, cb2, cw3, cb3, out);
}

// Round 5
// 12494.792 us; speedup vs baseline: 1.4918x; 1.0277x over previous
//
#include <hip/hip_runtime.h>
#include <hip/hip_bf16.h>
#include <math.h>

// Dims
#define B_SZ   32
#define L_SEQ  2048
#define BL     (B_SZ * L_SEQ)        // 65536
#define D_MODEL 256
#define D_INNER 512
#define D_STATE 16
#define D_CONV  4
#define LN_EPS  1e-5f
#define SEG    16                    // segments per sequence (parallel scan)
#define TSEG   (L_SEQ / SEG)         // 128 steps per segment

// ---------------------------------------------------------------------------
// input projection: h[row, c] = b[c] + sum_k x[row,k]*W[c,k]   (K=6)
// ---------------------------------------------------------------------------
__global__ __launch_bounds__(256) void input_proj_kernel(
    const float* __restrict__ x, const float* __restrict__ W,
    const float* __restrict__ b, float* __restrict__ h)
{
    size_t row = blockIdx.x;
    int c = threadIdx.x;
    const float* xr = x + row * 6;
    const float* wr = W + c * 6;
    float acc = b[c];
#pragma unroll
    for (int k = 0; k < 6; k++) acc += xr[k] * wr[k];
    h[row * D_MODEL + c] = acc;
}

// ---------------------------------------------------------------------------
// fp32 tiled GEMM:  C[M,N] = A[M,K] @ W[N,K]^T  (+ epilogue), strided A/C
// EPI 0: none, EPI 1: softplus(acc + bias[n]), EPI 2: acc + res (res==C ok)
// tile 128x128, BK=16, 256 threads, 8x8 micro-tile
// LDS row stride 132 (=4 mod 32): staging writes 4-way -> 2-way conflict (free)
// ---------------------------------------------------------------------------
template <int EPI>
__global__ __launch_bounds__(256) void gemm_f32(
    const float* __restrict__ A, int lda,
    const float* __restrict__ W,
    const float* __restrict__ bias, const float* __restrict__ res,
    float* __restrict__ C, int ldc, int M, int N, int K)
{
    __shared__ __align__(16) float As[16][132];
    __shared__ __align__(16) float Ws[16][132];
    const int tid = threadIdx.x;
    const int m0 = blockIdx.y * 128;
    const int n0 = blockIdx.x * 128;
    const int tx = tid & 15, ty = tid >> 4;

    float acc[8][8];
#pragma unroll
    for (int i = 0; i < 8; i++)
#pragma unroll
        for (int j = 0; j < 8; j++) acc[i][j] = 0.f;

    for (int k0 = 0; k0 < K; k0 += 16) {
#pragma unroll
        for (int it = 0; it < 2; it++) {
            int f = tid + it * 256;          // 0..511
            int row = f >> 2, kq = f & 3;
            float4 va = *(const float4*)(A + (size_t)(m0 + row) * lda + k0 + kq * 4);
            As[kq * 4 + 0][row] = va.x; As[kq * 4 + 1][row] = va.y;
            As[kq * 4 + 2][row] = va.z; As[kq * 4 + 3][row] = va.w;
            float4 vw = *(const float4*)(W + (size_t)(n0 + row) * K + k0 + kq * 4);
            Ws[kq * 4 + 0][row] = vw.x; Ws[kq * 4 + 1][row] = vw.y;
            Ws[kq * 4 + 2][row] = vw.z; Ws[kq * 4 + 3][row] = vw.w;
        }
        __syncthreads();
#pragma unroll
        for (int k = 0; k < 16; k++) {
            float a[8], b8[8];
            *(float4*)(a)     = *(const float4*)&As[k][ty * 8];
            *(float4*)(a + 4) = *(const float4*)&As[k][ty * 8 + 4];
            *(float4*)(b8)     = *(const float4*)&Ws[k][tx * 8];
            *(float4*)(b8 + 4) = *(const float4*)&Ws[k][tx * 8 + 4];
#pragma unroll
            for (int i = 0; i < 8; i++)
#pragma unroll
                for (int j = 0; j < 8; j++) acc[i][j] += a[i] * b8[j];
        }
        __syncthreads();
    }

#pragma unroll
    for (int i = 0; i < 8; i++) {
        size_t m = (size_t)(m0 + ty * 8 + i);
#pragma unroll
        for (int j = 0; j < 8; j++) {
            int n = n0 + tx * 8 + j;
            float v = acc[i][j];
            if (EPI == 1) {
                v += bias[n];
                v = (v > 20.f) ? v : log1pf(expf(v));
            } else if (EPI == 2) {
                v += res[m * ldc + n];
            }
            C[m * ldc + n] = v;
        }
    }
}

// ---------------------------------------------------------------------------
// causal depthwise conv (k=4, left pad 3) + SiLU, over R rows (whole batches).
// xz: (R,1024), xp = cols 0..511.  xc out: (R,512)
// ---------------------------------------------------------------------------
__global__ __launch_bounds__(256) void conv_silu_kernel(
    const float* __restrict__ xz, const float* __restrict__ cw,
    const float* __restrict__ cb, float* __restrict__ xc)
{
    size_t idx = (size_t)blockIdx.x * 256 + threadIdx.x;  // over R*512
    int d = (int)(idx & 511);
    int row = (int)(idx >> 9);
    int t = row & (L_SEQ - 1);
    float4 w = *(const float4*)(cw + d * 4);
    float acc = cb[d];
    if (t >= 3) {
        const float* xp = xz + (size_t)row * 1024 + d;
        acc += xp[-3 * 1024] * w.x + xp[-2 * 1024] * w.y +
               xp[-1 * 1024] * w.z + xp[0] * w.w;
    } else {
        const float wj[4] = {w.x, w.y, w.z, w.w};
#pragma unroll
        for (int j = 0; j < 4; j++) {
            int tj = t + j - 3;
            if (tj >= 0) acc += xz[(size_t)(row + j - 3) * 1024 + d] * wj[j];
        }
    }
    float sig = 1.f / (1.f + __expf(-acc));
    xc[idx] = acc * sig;
}

// ---------------------------------------------------------------------------
// x_proj: bc[row, c] = sum_k xc[row,k]*Wx[c,k]   (N=32, K=512)
// ---------------------------------------------------------------------------
__global__ __launch_bounds__(256) void xproj_kernel(
    const float* __restrict__ xc, const float* __restrict__ Wx,
    float* __restrict__ bc)
{
    int tid = threadIdx.x;
    int c = tid & 31, rl = tid >> 5;
    size_t row = (size_t)blockIdx.x * 8 + rl;
    const float* xr = xc + row * 512;
    const float* wr = Wx + c * 512;
    float acc = 0.f;
#pragma unroll 4
    for (int k = 0; k < 512; k += 4) {
        float4 xv = *(const float4*)(xr + k);
        float4 wv = *(const float4*)(wr + k);
        acc += xv.x * wv.x + xv.y * wv.y + xv.z * wv.z + xv.w * wv.w;
    }
    bc[row * 32 + c] = acc;
}

// ---------------------------------------------------------------------------
// Segment-parallel selective scan (rounds 3/4 were latency-bound at 1 wave/
// SIMD; the linear recurrence h_t = dA_t h_{t-1} + u_t decomposes exactly).
// Pass 1: per (b,d,n,segment): P = prod dA, Q = segment-local h (h_in=0).
// Pass 2: per (b,d,n): sequential combine over S=16 segments -> h_in(s).
// Pass 3: per segment with correct h_in: full scan, y, gate, store in-place.
// Block = 256 threads = 16 chains (d) x 16 states (n).
// grid pass1/3: blockIdx.x = ((b*32)+g)*16 + s.
// ---------------------------------------------------------------------------
__global__ __launch_bounds__(256) void scan_pass1_kernel(
    const float* __restrict__ xzdt,   // (R,1024): dt in cols 0..511
    const float* __restrict__ xc,     // (R,512)
    const float* __restrict__ bc,     // (R,32): B=0..15
    const float* __restrict__ A_log,  // (512,16)
    float* __restrict__ Pbuf,         // [SEG][nb*512*16]
    float* __restrict__ Qbuf,
    int nb)
{
    const int tid = threadIdx.x;
    const int chain = tid >> 4, n = tid & 15;
    const int s = blockIdx.x & (SEG - 1);
    const int g = (blockIdx.x >> 4) & 31;
    const int b = blockIdx.x >> 9;
    const int d = g * 16 + chain;

    const float A = -__expf(A_log[d * 16 + n]);
    const size_t row0 = (size_t)b * L_SEQ + (size_t)s * TSEG;
    const float* dtp = xzdt + row0 * 1024 + d;
    const float* xcp = xc + row0 * 512 + d;
    const float* bp  = bc + row0 * 32 + n;

    float h = 0.f, P = 1.f;
#pragma unroll 4
    for (int t = 0; t < TSEG; t++) {
        const float dtv = dtp[(size_t)t * 1024];
        const float xcv = xcp[(size_t)t * 512];
        const float Bv  = bp[(size_t)t * 32];
        const float dA = __expf(A * dtv);
        h = fmaf(dA, h, (dtv * Bv) * xcv);
        P *= dA;
    }
    const int N = nb * 512 * 16;
    const int idx = (b * 512 + d) * 16 + n;
    Pbuf[s * N + idx] = P;
    Qbuf[s * N + idx] = h;
}

__global__ __launch_bounds__(256) void scan_pass2_kernel(
    const float* __restrict__ Pbuf, const float* __restrict__ Qbuf,
    float* __restrict__ Hin, int N)
{
    const int idx = blockIdx.x * 256 + threadIdx.x;
    float run = 0.f;
#pragma unroll
    for (int s = 0; s < SEG; s++) {
        Hin[s * N + idx] = run;
        run = fmaf(Pbuf[s * N + idx], run, Qbuf[s * N + idx]);
    }
}

__global__ __launch_bounds__(256) void scan_pass3_kernel(
    float* xzdt,                      // (R,1024): dt -> gated y (cols 0..511), z in 512..1023
    const float* __restrict__ xc,     // (R,512)
    const float* __restrict__ bc,     // (R,32): B=0..15, C=16..31
    const float* __restrict__ A_log,  // (512,16)
    const float* __restrict__ Dp,     // (512)
    const float* __restrict__ Hin,    // [SEG][nb*512*16]
    int nb)
{
    const int tid = threadIdx.x;
    const int chain = tid >> 4, n = tid & 15;
    const int s = blockIdx.x & (SEG - 1);
    const int g = (blockIdx.x >> 4) & 31;
    const int b = blockIdx.x >> 9;
    const int d = g * 16 + chain;

    const float A = -__expf(A_log[d * 16 + n]);
    const float Dd = Dp[d];
    const int N = nb * 512 * 16;
    const int idx = (b * 512 + d) * 16 + n;
    float h = Hin[s * N + idx];

    const size_t row0 = (size_t)b * L_SEQ + (size_t)s * TSEG;
    float* dtp = xzdt + row0 * 1024 + d;
    const float* zp = xzdt + row0 * 1024 + 512 + d;
    const float* xcp = xc + row0 * 512 + d;
    const float* bp  = bc + row0 * 32 + n;

#pragma unroll 4
    for (int t = 0; t < TSEG; t++) {
        const float dtv = dtp[(size_t)t * 1024];
        const float xcv = xcp[(size_t)t * 512];
        const float zv  = zp[(size_t)t * 1024];
        const float Bv  = bp[(size_t)t * 32];
        const float Cv  = bp[(size_t)t * 32 + 16];
        const float dA = __expf(A * dtv);
        h = fmaf(dA, h, (dtv * Bv) * xcv);
        float pv = h * Cv;
        pv += __shfl_xor(pv, 8, 16);
        pv += __shfl_xor(pv, 4, 16);
        pv += __shfl_xor(pv, 2, 16);
        pv += __shfl_xor(pv, 1, 16);
        if (n == 0) {
            const float sig = 1.f / (1.f + __expf(-zv));
            dtp[(size_t)t * 1024] = (pv + xcv * Dd) * (zv * sig);
        }
    }
}

// ---------------------------------------------------------------------------
// LayerNorm over 256 cols, in-place safe; one wave per row, 4 rows per block
// ---------------------------------------------------------------------------
__global__ __launch_bounds__(256) void ln256_kernel(
    const float* __restrict__ in, const float* __restrict__ g,
    const float* __restrict__ b, float* __restrict__ out)
{
    int wave = threadIdx.x >> 6, lane = threadIdx.x & 63;
    size_t row = (size_t)blockIdx.x * 4 + wave;
    const float* p = in + row * 256 + lane * 4;
    float4 v = *(const float4*)p;
    float s = v.x + v.y + v.z + v.w;
    float sq = v.x * v.x + v.y * v.y + v.z * v.z + v.w * v.w;
#pragma unroll
    for (int o = 32; o; o >>= 1) {
        s += __shfl_xor(s, o, 64);
        sq += __shfl_xor(sq, o, 64);
    }
    float m = s * (1.f / 256.f);
    float var = sq * (1.f / 256.f) - m * m;
    float rs = 1.f / sqrtf(var + LN_EPS);
    float4 gg = *(const float4*)(g + lane * 4);
    float4 bb = *(const float4*)(b + lane * 4);
    float4 o4;
    o4.x = (v.x - m) * rs * gg.x + bb.x;
    o4.y = (v.y - m) * rs * gg.y + bb.y;
    o4.z = (v.z - m) * rs * gg.z + bb.z;
    o4.w = (v.w - m) * rs * gg.w + bb.w;
    *(float4*)(out + row * 256 + lane * 4) = o4;
}

// ---------------------------------------------------------------------------
// head: tick-LN -> fusion (gelu, LN, linear) -> classifier.  1 block / batch row
// ---------------------------------------------------------------------------
__device__ __forceinline__ float gelu_exact(float x) {
    return 0.5f * x * (1.f + erff(x * 0.70710678118654752f));
}

__global__ __launch_bounds__(256) void head_kernel(
    const float* __restrict__ h, const float* __restrict__ sent,
    const float* __restrict__ ta,
    const float* __restrict__ eng, const float* __restrict__ enb,
    const float* __restrict__ w1, const float* __restrict__ b1,
    const float* __restrict__ lng, const float* __restrict__ lnb,
    const float* __restrict__ w2, const float* __restrict__ b2,
    const float* __restrict__ cw1, const float* __restrict__ cb1,
    const float* __restrict__ cw2, const float* __restrict__ cb2,
    const float* __restrict__ cw3, const float* __restrict__ cb3,
    float* __restrict__ out)
{
    __shared__ __align__(16) float comb[1036];
    __shared__ __align__(16) float fbuf[256];
    __shared__ float rs_[4], rq_[4];
    const int r = blockIdx.x, tid = threadIdx.x;

    // ---- tick = LN(h[:, L-1]) ----
    float v = h[((size_t)r * L_SEQ + (L_SEQ - 1)) * 256 + tid];
    float s = v, sq = v * v;
#pragma unroll
    for (int o = 32; o; o >>= 1) { s += __shfl_xor(s, o, 64); sq += __shfl_xor(sq, o, 64); }
    if ((tid & 63) == 0) { rs_[tid >> 6] = s; rq_[tid >> 6] = sq; }
    __syncthreads();
    s = rs_[0] + rs_[1] + rs_[2] + rs_[3];
    sq = rq_[0] + rq_[1] + rq_[2] + rq_[3];
    float m = s * (1.f / 256.f);
    float var = sq * (1.f / 256.f) - m * m;
    float rstd = 1.f / sqrtf(var + LN_EPS);
    comb[tid] = (v - m) * rstd * eng[tid] + enb[tid];
    comb[256 + tid] = sent[(size_t)r * 768 + tid];
    comb[512 + tid] = sent[(size_t)r * 768 + 256 + tid];
    comb[768 + tid] = sent[(size_t)r * 768 + 512 + tid];
    if (tid < 12) comb[1024 + tid] = ta[(size_t)r * 12 + tid];
    __syncthreads();

    // ---- f1 = gelu(comb @ w1^T + b1) ----
    float acc = b1[tid];
    {
        const float* wr = w1 + (size_t)tid * 1036;
        for (int k = 0; k < 1036; k += 4) {
            float4 wv = *(const float4*)(wr + k);
            float4 cv = *(const float4*)(comb + k);
            acc += wv.x * cv.x + wv.y * cv.y + wv.z * cv.z + wv.w * cv.w;
        }
    }
    float f1 = gelu_exact(acc);

    // ---- LN(f1) ----
    s = f1; sq = f1 * f1;
#pragma unroll
    for (int o = 32; o; o >>= 1) { s += __shfl_xor(s, o, 64); sq += __shfl_xor(sq, o, 64); }
    if ((tid & 63) == 0) { rs_[tid >> 6] = s; rq_[tid >> 6] = sq; }
    __syncthreads();
    s = rs_[0] + rs_[1] + rs_[2] + rs_[3];
    sq = rq_[0] + rq_[1] + rq_[2] + rq_[3];
    m = s * (1.f / 256.f);
    var = sq * (1.f / 256.f) - m * m;
    rstd = 1.f / sqrtf(var + LN_EPS);
    fbuf[tid] = (f1 - m) * rstd * lng[tid] + lnb[tid];
    __syncthreads();

    // ---- f2 = fbuf @ w2^T + b2 ----
    acc = b2[tid];
    {
        const float* wr = w2 + (size_t)tid * 256;
        for (int k = 0; k < 256; k += 4) {
            float4 wv = *(const float4*)(wr + k);
            float4 cv = *(const float4*)(fbuf + k);
            acc += wv.x * cv.x + wv.y * cv.y + wv.z * cv.z + wv.w * cv.w;
        }
    }
    __syncthreads();
    comb[tid] = acc;     // f2 lives in comb[0..255]
    __syncthreads();

    // ---- c1 = gelu(f2 @ cw1^T + cb1), 128 ----
    if (tid < 128) {
        float a = cb1[tid];
        const float* wr = cw1 + (size_t)tid * 256;
        for (int k = 0; k < 256; k += 4) {
            float4 wv = *(const float4*)(wr + k);
            float4 cv = *(const float4*)(comb + k);
            a += wv.x * cv.x + wv.y * cv.y + wv.z * cv.z + wv.w * cv.w;
        }
        fbuf[tid] = gelu_exact(a);
    }
    __syncthreads();

    // ---- c2 = gelu(c1 @ cw2^T + cb2), 64 ----
    float c2v = 0.f;
    if (tid < 64) {
        float a = cb2[tid];
        const float* wr = cw2 + (size_t)tid * 128;
        for (int k = 0; k < 128; k += 4) {
            float4 wv = *(const float4*)(wr + k);
            float4 cv = *(const float4*)(fbuf + k);
            a += wv.x * cv.x + wv.y * cv.y + wv.z * cv.z + wv.w * cv.w;
        }
        c2v = gelu_exact(a);
    }
    __syncthreads();
    if (tid < 64) comb[tid] = c2v;
    __syncthreads();

    // ---- logits ----
    if (tid < 3) {
        float a = cb3[tid];
        const float* wr = cw3 + (size_t)tid * 64;
        for (int k = 0; k < 64; k++) a += wr[k] * comb[k];
        out[(size_t)r * 3 + tid] = a;
    }
}

// ---------------------------------------------------------------------------
extern "C" void kernel_launch(void* const* d_in, const int* in_sizes, int n_in,
                              void* d_out, int out_size, void* d_ws, size_t ws_size,
                              hipStream_t stream) {
    const float* x    = (const float*)d_in[0];
    const float* sent = (const float*)d_in[1];
    const float* ta   = (const float*)d_in[2];
    const float* ipw  = (const float*)d_in[3];
    const float* ipb  = (const float*)d_in[4];
    const float* inw  = (const float*)d_in[5];
    const float* cw   = (const float*)d_in[6];
    const float* cb   = (const float*)d_in[7];
    const float* xpw  = (const float*)d_in[8];
    const float* dtw  = (const float*)d_in[9];
    const float* dtb  = (const float*)d_in[10];
    const float* alog = (const float*)d_in[11];
    const float* Dp   = (const float*)d_in[12];
    const float* opw  = (const float*)d_in[13];
    const float* lng  = (const float*)d_in[14];
    const float* lnb  = (const float*)d_in[15];
    const float* eng  = (const float*)d_in[16];
    const float* enb  = (const float*)d_in[17];
    const float* fw1  = (const float*)d_in[18];
    const float* fb1  = (const float*)d_in[19];
    const float* flg  = (const float*)d_in[20];
    const float* flb  = (const float*)d_in[21];
    const float* fw2  = (const float*)d_in[22];
    const float* fb2  = (const float*)d_in[23];
    const float* cw1  = (const float*)d_in[24];
    const float* cb1  = (const float*)d_in[25];
    const float* cw2  = (const float*)d_in[26];
    const float* cb2  = (const float*)d_in[27];
    const float* cw3  = (const float*)d_in[28];
    const float* cb3  = (const float*)d_in[29];
    float* out = (float*)d_out;

    // --- workspace: h (BL*256, persistent) + per-chunk temporaries:
    //     xz R*1024 + xc R*512 + bc R*32 = R*1568 floats
    //   + segment-scan buffers P,Q,Hin: 3 * SEG * nb*512*16 = nb*393216 floats.
    // Chunk over whole batches until it fits ws_size (deterministic per ws_size).
    int c = 1;
    while (c < 32 &&
           ((size_t)BL * 256 + ((size_t)BL / c) * 1568 +
            (size_t)(B_SZ / c) * 393216) * sizeof(float) > ws_size)
        c <<= 1;
    const size_t R = BL / c;        // rows per chunk (multiple of L_SEQ)
    const int nb = B_SZ / c;        // batches per chunk
    const int Nseg = nb * 512 * 16; // (b,d,n) states per chunk

    float* ws = (float*)d_ws;
    float* hbuf  = ws;                         // BL*256 (persistent)
    float* xzbuf = hbuf + (size_t)BL * 256;    // R*1024
    float* xcbuf = xzbuf + R * 1024;           // R*512
    float* bcbuf = xcbuf + R * 512;            // R*32
    float* Pbuf  = bcbuf + R * 32;             // SEG*Nseg
    float* Qbuf  = Pbuf + (size_t)SEG * Nseg;  // SEG*Nseg
    float* Hin   = Qbuf + (size_t)SEG * Nseg;  // SEG*Nseg

    input_proj_kernel<<<BL, 256, 0, stream>>>(x, ipw, ipb, hbuf);

    for (int l = 0; l < 4; l++) {
        const float* inw_l = inw + (size_t)l * 1024 * 256;
        const float* cw_l  = cw  + (size_t)l * 512 * 4;
        const float* cb_l  = cb  + (size_t)l * 512;
        const float* xpw_l = xpw + (size_t)l * 32 * 512;
        const float* dtw_l = dtw + (size_t)l * 512 * 512;
        const float* dtb_l = dtb + (size_t)l * 512;
        const float* al_l  = alog + (size_t)l * 512 * 16;
        const float* Dp_l  = Dp  + (size_t)l * 512;
        const float* opw_l = opw + (size_t)l * 256 * 512;
        const float* lng_l = lng + (size_t)l * 256;
        const float* lnb_l = lnb + (size_t)l * 256;

        for (int k = 0; k < c; k++) {
            float* hck = hbuf + (size_t)k * R * 256;

            // xz = h @ Wi^T            (R x 1024)
            gemm_f32<0><<<dim3(1024 / 128, R / 128), 256, 0, stream>>>(
                hck, 256, inw_l, nullptr, nullptr, xzbuf, 1024, (int)R, 1024, 256);
            // xc = silu(causal dwconv(xp) + cb)
            conv_silu_kernel<<<(unsigned)(R * 2), 256, 0, stream>>>(
                xzbuf, cw_l, cb_l, xcbuf);
            // dt = softplus(xc @ Wdt^T + bdt)  -> xz cols 0..511 (xp is dead)
            gemm_f32<1><<<dim3(512 / 128, R / 128), 256, 0, stream>>>(
                xcbuf, 512, dtw_l, dtb_l, nullptr, xzbuf, 1024, (int)R, 512, 512);
            // bc = xc @ Wx^T            (R x 32)
            xproj_kernel<<<(unsigned)(R / 8), 256, 0, stream>>>(xcbuf, xpw_l, bcbuf);
            // segment-parallel selective scan + gate (in-place over dt half)
            scan_pass1_kernel<<<(unsigned)(nb * 32 * SEG), 256, 0, stream>>>(
                xzbuf, xcbuf, bcbuf, al_l, Pbuf, Qbuf, nb);
            scan_pass2_kernel<<<(unsigned)(Nseg / 256), 256, 0, stream>>>(
                Pbuf, Qbuf, Hin, Nseg);
            scan_pass3_kernel<<<(unsigned)(nb * 32 * SEG), 256, 0, stream>>>(
                xzbuf, xcbuf, bcbuf, al_l, Dp_l, Hin, nb);
            // h += y @ Wo^T  (in-place residual), then LN in-place
            gemm_f32<2><<<dim3(256 / 128, R / 128), 256, 0, stream>>>(
                xzbuf, 1024, opw_l, nullptr, hck, hck, 256, (int)R, 256, 512);
            ln256_kernel<<<(unsigned)(R / 4), 256, 0, stream>>>(
                hck, lng_l, lnb_l, hck);
        }
    }

    head_kernel<<<32, 256, 0, stream>>>(hbuf, sent, ta, eng, enb,
                                        fw1, fb1, flg, flb, fw2, fb2,
                                        cw1, cb1, cw2, cb2, cw3, cb3, out);
}

// Round 6
// 7390.889 us; speedup vs baseline: 2.5220x; 1.6906x over previous
//
#include <hip/hip_runtime.h>
#include <hip/hip_bf16.h>
#include <math.h>

// Dims
#define B_SZ   32
#define L_SEQ  2048
#define BL     (B_SZ * L_SEQ)        // 65536
#define D_MODEL 256
#define D_INNER 512
#define D_STATE 16
#define D_CONV  4
#define LN_EPS  1e-5f
#define SEG    16                    // segments per sequence (parallel scan)
#define TSEG   (L_SEQ / SEG)         // 128 steps per segment

typedef short  s16x8 __attribute__((ext_vector_type(8)));   // 8 bf16 (4 VGPRs)
typedef float  f32x4 __attribute__((ext_vector_type(4)));

// float -> bf16 (RNE), as raw ushort
__device__ __forceinline__ unsigned short f2bf(float x) {
    unsigned int u = __float_as_uint(x);
    unsigned int r = (u + 0x7fffu + ((u >> 16) & 1u)) >> 16;
    return (unsigned short)r;
}
__device__ __forceinline__ float bf2f(unsigned short h) {
    return __uint_as_float((unsigned int)h << 16);
}

// ---------------------------------------------------------------------------
// weight pre-convert: fp32 -> (hi, lo) bf16 pair.  a ~= hi + lo, err ~2^-18.
// ---------------------------------------------------------------------------
__global__ __launch_bounds__(256) void convert_w_kernel(
    const float* __restrict__ src, unsigned short* __restrict__ hi,
    unsigned short* __restrict__ lo, int n)
{
    int i = blockIdx.x * 256 + threadIdx.x;
    if (i < n) {
        float x = src[i];
        unsigned short h = f2bf(x);
        hi[i] = h;
        lo[i] = f2bf(x - bf2f(h));
    }
}

// ---------------------------------------------------------------------------
// input projection: h[row, c] = b[c] + sum_k x[row,k]*W[c,k]   (K=6)
// ---------------------------------------------------------------------------
__global__ __launch_bounds__(256) void input_proj_kernel(
    const float* __restrict__ x, const float* __restrict__ W,
    const float* __restrict__ b, float* __restrict__ h)
{
    size_t row = blockIdx.x;
    int c = threadIdx.x;
    const float* xr = x + row * 6;
    const float* wr = W + c * 6;
    float acc = b[c];
#pragma unroll
    for (int k = 0; k < 6; k++) acc += xr[k] * wr[k];
    h[row * D_MODEL + c] = acc;
}

// ---------------------------------------------------------------------------
// split-bf16 MFMA GEMM:  C[M,N] = A[M,K] @ W[N,K]^T (+ epilogue)
// A fp32 (converted to hi/lo bf16 during LDS staging); W pre-split hi/lo bf16.
// Each product = Ahi*Bhi + Ahi*Blo + Alo*Bhi  (3 MFMA) -> ~fp32 precision.
// 128x128 tile, BK=32, 256 thr = 4 waves (2x2 of 64x64), 16x16x32 MFMA.
// LDS k-stride 40 (80B rows): fragment ds_read_b128 2-way conflict = free.
// EPI 0: none, 1: softplus(acc+bias[n]), 2: acc + res (res==C in-place ok)
// ---------------------------------------------------------------------------
#define LDK 40
template <int EPI>
__global__ __launch_bounds__(256) void gemm_bf16s(
    const float* __restrict__ A, int lda,
    const unsigned short* __restrict__ Whi, const unsigned short* __restrict__ Wlo,
    const float* __restrict__ bias, const float* __restrict__ res,
    float* __restrict__ C, int ldc, int M, int N, int K)
{
    __shared__ unsigned short Ah[128 * LDK], Al[128 * LDK];
    __shared__ unsigned short Bh[128 * LDK], Bl[128 * LDK];
    const int tid = threadIdx.x;
    const int m0 = blockIdx.y * 128, n0 = blockIdx.x * 128;
    const int lane = tid & 63, wave = tid >> 6;
    const int quad = lane >> 4, l15 = lane & 15;
    const int wm = wave & 1, wn = wave >> 1;

    f32x4 acc[4][4];
#pragma unroll
    for (int mi = 0; mi < 4; mi++)
#pragma unroll
        for (int ni = 0; ni < 4; ni++) acc[mi][ni] = (f32x4){0.f, 0.f, 0.f, 0.f};

    for (int k0 = 0; k0 < K; k0 += 32) {
        // ---- stage: 128 rows x 32 k.  1024 groups of 4 elements.
#pragma unroll
        for (int i = 0; i < 4; i++) {
            int idx = i * 256 + tid;
            int row = idx >> 3, kq = (idx & 7) << 2;
            float4 v = *(const float4*)(A + (size_t)(m0 + row) * lda + k0 + kq);
            ushort4 h4, l4;
            h4.x = f2bf(v.x); l4.x = f2bf(v.x - bf2f(h4.x));
            h4.y = f2bf(v.y); l4.y = f2bf(v.y - bf2f(h4.y));
            h4.z = f2bf(v.z); l4.z = f2bf(v.z - bf2f(h4.z));
            h4.w = f2bf(v.w); l4.w = f2bf(v.w - bf2f(h4.w));
            *(ushort4*)&Ah[row * LDK + kq] = h4;
            *(ushort4*)&Al[row * LDK + kq] = l4;
            ushort4 wh = *(const ushort4*)(Whi + (size_t)(n0 + row) * K + k0 + kq);
            ushort4 wl = *(const ushort4*)(Wlo + (size_t)(n0 + row) * K + k0 + kq);
            *(ushort4*)&Bh[row * LDK + kq] = wh;
            *(ushort4*)&Bl[row * LDK + kq] = wl;
        }
        __syncthreads();

        // ---- fragments: lane holds X[m=l15][k=quad*8+j]
        s16x8 ah[4], al[4], bh[4], bl[4];
#pragma unroll
        for (int i = 0; i < 4; i++) {
            ah[i] = *(s16x8*)&Ah[(wm * 64 + i * 16 + l15) * LDK + quad * 8];
            al[i] = *(s16x8*)&Al[(wm * 64 + i * 16 + l15) * LDK + quad * 8];
            bh[i] = *(s16x8*)&Bh[(wn * 64 + i * 16 + l15) * LDK + quad * 8];
            bl[i] = *(s16x8*)&Bl[(wn * 64 + i * 16 + l15) * LDK + quad * 8];
        }
#pragma unroll
        for (int mi = 0; mi < 4; mi++)
#pragma unroll
            for (int ni = 0; ni < 4; ni++) {
                acc[mi][ni] = __builtin_amdgcn_mfma_f32_16x16x32_bf16(
                    ah[mi], bh[ni], acc[mi][ni], 0, 0, 0);
                acc[mi][ni] = __builtin_amdgcn_mfma_f32_16x16x32_bf16(
                    ah[mi], bl[ni], acc[mi][ni], 0, 0, 0);
                acc[mi][ni] = __builtin_amdgcn_mfma_f32_16x16x32_bf16(
                    al[mi], bh[ni], acc[mi][ni], 0, 0, 0);
            }
        __syncthreads();
    }

    // ---- epilogue: D row = quad*4 + reg, col = l15
#pragma unroll
    for (int mi = 0; mi < 4; mi++) {
        const int mrow = m0 + wm * 64 + mi * 16 + quad * 4;
#pragma unroll
        for (int ni = 0; ni < 4; ni++) {
            const int ncol = n0 + wn * 64 + ni * 16 + l15;
#pragma unroll
            for (int r = 0; r < 4; r++) {
                float v = acc[mi][ni][r];
                if (EPI == 1) {
                    v += bias[ncol];
                    v = (v > 20.f) ? v : log1pf(expf(v));
                } else if (EPI == 2) {
                    v += res[(size_t)(mrow + r) * ldc + ncol];
                }
                C[(size_t)(mrow + r) * ldc + ncol] = v;
            }
        }
    }
}

// ---------------------------------------------------------------------------
// causal depthwise conv (k=4, left pad 3) + SiLU, over R rows (whole batches).
// xz: (R,1024), xp = cols 0..511.  xc out: (R,512)
// ---------------------------------------------------------------------------
__global__ __launch_bounds__(256) void conv_silu_kernel(
    const float* __restrict__ xz, const float* __restrict__ cw,
    const float* __restrict__ cb, float* __restrict__ xc)
{
    size_t idx = (size_t)blockIdx.x * 256 + threadIdx.x;  // over R*512
    int d = (int)(idx & 511);
    int row = (int)(idx >> 9);
    int t = row & (L_SEQ - 1);
    float4 w = *(const float4*)(cw + d * 4);
    float acc = cb[d];
    if (t >= 3) {
        const float* xp = xz + (size_t)row * 1024 + d;
        acc += xp[-3 * 1024] * w.x + xp[-2 * 1024] * w.y +
               xp[-1 * 1024] * w.z + xp[0] * w.w;
    } else {
        const float wj[4] = {w.x, w.y, w.z, w.w};
#pragma unroll
        for (int j = 0; j < 4; j++) {
            int tj = t + j - 3;
            if (tj >= 0) acc += xz[(size_t)(row + j - 3) * 1024 + d] * wj[j];
        }
    }
    float sig = 1.f / (1.f + __expf(-acc));
    xc[idx] = acc * sig;
}

// ---------------------------------------------------------------------------
// x_proj: bc[row, c] = sum_k xc[row,k]*Wx[c,k]   (N=32, K=512)
// ---------------------------------------------------------------------------
__global__ __launch_bounds__(256) void xproj_kernel(
    const float* __restrict__ xc, const float* __restrict__ Wx,
    float* __restrict__ bc)
{
    int tid = threadIdx.x;
    int c = tid & 31, rl = tid >> 5;
    size_t row = (size_t)blockIdx.x * 8 + rl;
    const float* xr = xc + row * 512;
    const float* wr = Wx + c * 512;
    float acc = 0.f;
#pragma unroll 4
    for (int k = 0; k < 512; k += 4) {
        float4 xv = *(const float4*)(xr + k);
        float4 wv = *(const float4*)(wr + k);
        acc += xv.x * wv.x + xv.y * wv.y + xv.z * wv.z + xv.w * wv.w;
    }
    bc[row * 32 + c] = acc;
}

// ---------------------------------------------------------------------------
// Segment-parallel selective scan, 4 states per lane (round-5 pass3 was
// VALU-issue-bound: 16 redundant lanes/chain + 64 shfls per (b,d,t)).
// Lane = (d, nq): owns n = 4nq..4nq+3 in registers.  Block 256 thr = 64 d's.
// grid pass1/3: blockIdx = ((b*8)+g)*SEG + s, g covers d in [64g, 64g+64).
// Pass 1: P[4] = prod dA, Q[4] = segment-local h.
// Pass 2: sequential combine over segments (flat over (b,d,n)).
// Pass 3: re-scan with Hin, y via 2 width-4 shfls, gate, store in-place.
// ---------------------------------------------------------------------------
__global__ __launch_bounds__(256) void scan_pass1_kernel(
    const float* __restrict__ xzdt,   // (R,1024): dt in cols 0..511
    const float* __restrict__ xc,     // (R,512)
    const float* __restrict__ bc,     // (R,32): B=0..15
    const float* __restrict__ A_log,  // (512,16)
    float* __restrict__ Pbuf,         // [SEG][nb*512*16]
    float* __restrict__ Qbuf,
    int nb)
{
    const int tid = threadIdx.x;
    const int dl = tid >> 2, nq = tid & 3;
    const int s = blockIdx.x & (SEG - 1);
    const int g = (blockIdx.x >> 4) & 7;
    const int b = blockIdx.x >> 7;
    const int d = g * 64 + dl;

    float4 Av = *(const float4*)(A_log + d * 16 + nq * 4);
    const float A0 = -__expf(Av.x), A1 = -__expf(Av.y);
    const float A2 = -__expf(Av.z), A3 = -__expf(Av.w);

    const size_t row0 = (size_t)b * L_SEQ + (size_t)s * TSEG;
    const float* dtp = xzdt + row0 * 1024 + d;
    const float* xcp = xc + row0 * 512 + d;
    const float* bp  = bc + row0 * 32 + nq * 4;

    float h0 = 0.f, h1 = 0.f, h2 = 0.f, h3 = 0.f;
    float P0 = 1.f, P1 = 1.f, P2 = 1.f, P3 = 1.f;
#pragma unroll 4
    for (int t = 0; t < TSEG; t++) {
        const float dt = dtp[(size_t)t * 1024];
        const float xcv = xcp[(size_t)t * 512];
        const float4 Bv = *(const float4*)(bp + (size_t)t * 32);
        const float dtxc = dt * xcv;
        const float e0 = __expf(A0 * dt), e1 = __expf(A1 * dt);
        const float e2 = __expf(A2 * dt), e3 = __expf(A3 * dt);
        h0 = fmaf(e0, h0, dtxc * Bv.x); P0 *= e0;
        h1 = fmaf(e1, h1, dtxc * Bv.y); P1 *= e1;
        h2 = fmaf(e2, h2, dtxc * Bv.z); P2 *= e2;
        h3 = fmaf(e3, h3, dtxc * Bv.w); P3 *= e3;
    }
    const int N = nb * 512 * 16;
    const int idx = (b * 512 + d) * 16 + nq * 4;
    *(float4*)(Pbuf + (size_t)s * N + idx) = make_float4(P0, P1, P2, P3);
    *(float4*)(Qbuf + (size_t)s * N + idx) = make_float4(h0, h1, h2, h3);
}

__global__ __launch_bounds__(256) void scan_pass2_kernel(
    const float* __restrict__ Pbuf, const float* __restrict__ Qbuf,
    float* __restrict__ Hin, int N)
{
    const int idx = blockIdx.x * 256 + threadIdx.x;
    float run = 0.f;
#pragma unroll
    for (int s = 0; s < SEG; s++) {
        Hin[(size_t)s * N + idx] = run;
        run = fmaf(Pbuf[(size_t)s * N + idx], run, Qbuf[(size_t)s * N + idx]);
    }
}

__global__ __launch_bounds__(256) void scan_pass3_kernel(
    float* xzdt,                      // (R,1024): dt -> gated y, z in 512..1023
    const float* __restrict__ xc,     // (R,512)
    const float* __restrict__ bc,     // (R,32): B=0..15, C=16..31
    const float* __restrict__ A_log,  // (512,16)
    const float* __restrict__ Dp,     // (512)
    const float* __restrict__ Hin,    // [SEG][nb*512*16]
    int nb)
{
    const int tid = threadIdx.x;
    const int dl = tid >> 2, nq = tid & 3;
    const int s = blockIdx.x & (SEG - 1);
    const int g = (blockIdx.x >> 4) & 7;
    const int b = blockIdx.x >> 7;
    const int d = g * 64 + dl;

    float4 Av = *(const float4*)(A_log + d * 16 + nq * 4);
    const float A0 = -__expf(Av.x), A1 = -__expf(Av.y);
    const float A2 = -__expf(Av.z), A3 = -__expf(Av.w);
    const float Dd = Dp[d];

    const int N = nb * 512 * 16;
    const int idx = (b * 512 + d) * 16 + nq * 4;
    float4 h4 = *(const float4*)(Hin + (size_t)s * N + idx);
    float h0 = h4.x, h1 = h4.y, h2 = h4.z, h3 = h4.w;

    const size_t row0 = (size_t)b * L_SEQ + (size_t)s * TSEG;
    float* dtp = xzdt + row0 * 1024 + d;
    const float* zp = xzdt + row0 * 1024 + 512 + d;
    const float* xcp = xc + row0 * 512 + d;
    const float* bp  = bc + row0 * 32 + nq * 4;

#pragma unroll 4
    for (int t = 0; t < TSEG; t++) {
        const float dt = dtp[(size_t)t * 1024];
        const float xcv = xcp[(size_t)t * 512];
        const float zv  = zp[(size_t)t * 1024];
        const float4 Bv = *(const float4*)(bp + (size_t)t * 32);
        const float4 Cv = *(const float4*)(bp + (size_t)t * 32 + 16);
        const float dtxc = dt * xcv;
        const float e0 = __expf(A0 * dt), e1 = __expf(A1 * dt);
        const float e2 = __expf(A2 * dt), e3 = __expf(A3 * dt);
        h0 = fmaf(e0, h0, dtxc * Bv.x);
        h1 = fmaf(e1, h1, dtxc * Bv.y);
        h2 = fmaf(e2, h2, dtxc * Bv.z);
        h3 = fmaf(e3, h3, dtxc * Bv.w);
        float pv = h0 * Cv.x + h1 * Cv.y + h2 * Cv.z + h3 * Cv.w;
        pv += __shfl_xor(pv, 1, 4);
        pv += __shfl_xor(pv, 2, 4);
        if (nq == 0) {
            const float sig = 1.f / (1.f + __expf(-zv));
            dtp[(size_t)t * 1024] = (pv + xcv * Dd) * (zv * sig);
        }
    }
}

// ---------------------------------------------------------------------------
// LayerNorm over 256 cols, in-place safe; one wave per row, 4 rows per block
// ---------------------------------------------------------------------------
__global__ __launch_bounds__(256) void ln256_kernel(
    const float* __restrict__ in, const float* __restrict__ g,
    const float* __restrict__ b, float* __restrict__ out)
{
    int wave = threadIdx.x >> 6, lane = threadIdx.x & 63;
    size_t row = (size_t)blockIdx.x * 4 + wave;
    const float* p = in + row * 256 + lane * 4;
    float4 v = *(const float4*)p;
    float s = v.x + v.y + v.z + v.w;
    float sq = v.x * v.x + v.y * v.y + v.z * v.z + v.w * v.w;
#pragma unroll
    for (int o = 32; o; o >>= 1) {
        s += __shfl_xor(s, o, 64);
        sq += __shfl_xor(sq, o, 64);
    }
    float m = s * (1.f / 256.f);
    float var = sq * (1.f / 256.f) - m * m;
    float rs = 1.f / sqrtf(var + LN_EPS);
    float4 gg = *(const float4*)(g + lane * 4);
    float4 bb = *(const float4*)(b + lane * 4);
    float4 o4;
    o4.x = (v.x - m) * rs * gg.x + bb.x;
    o4.y = (v.y - m) * rs * gg.y + bb.y;
    o4.z = (v.z - m) * rs * gg.z + bb.z;
    o4.w = (v.w - m) * rs * gg.w + bb.w;
    *(float4*)(out + row * 256 + lane * 4) = o4;
}

// ---------------------------------------------------------------------------
// head: tick-LN -> fusion (gelu, LN, linear) -> classifier.  1 block / batch row
// ---------------------------------------------------------------------------
__device__ __forceinline__ float gelu_exact(float x) {
    return 0.5f * x * (1.f + erff(x * 0.70710678118654752f));
}

__global__ __launch_bounds__(256) void head_kernel(
    const float* __restrict__ h, const float* __restrict__ sent,
    const float* __restrict__ ta,
    const float* __restrict__ eng, const float* __restrict__ enb,
    const float* __restrict__ w1, const float* __restrict__ b1,
    const float* __restrict__ lng, const float* __restrict__ lnb,
    const float* __restrict__ w2, const float* __restrict__ b2,
    const float* __restrict__ cw1, const float* __restrict__ cb1,
    const float* __restrict__ cw2, const float* __restrict__ cb2,
    const float* __restrict__ cw3, const float* __restrict__ cb3,
    float* __restrict__ out)
{
    __shared__ __align__(16) float comb[1036];
    __shared__ __align__(16) float fbuf[256];
    __shared__ float rs_[4], rq_[4];
    const int r = blockIdx.x, tid = threadIdx.x;

    // ---- tick = LN(h[:, L-1]) ----
    float v = h[((size_t)r * L_SEQ + (L_SEQ - 1)) * 256 + tid];
    float s = v, sq = v * v;
#pragma unroll
    for (int o = 32; o; o >>= 1) { s += __shfl_xor(s, o, 64); sq += __shfl_xor(sq, o, 64); }
    if ((tid & 63) == 0) { rs_[tid >> 6] = s; rq_[tid >> 6] = sq; }
    __syncthreads();
    s = rs_[0] + rs_[1] + rs_[2] + rs_[3];
    sq = rq_[0] + rq_[1] + rq_[2] + rq_[3];
    float m = s * (1.f / 256.f);
    float var = sq * (1.f / 256.f) - m * m;
    float rstd = 1.f / sqrtf(var + LN_EPS);
    comb[tid] = (v - m) * rstd * eng[tid] + enb[tid];
    comb[256 + tid] = sent[(size_t)r * 768 + tid];
    comb[512 + tid] = sent[(size_t)r * 768 + 256 + tid];
    comb[768 + tid] = sent[(size_t)r * 768 + 512 + tid];
    if (tid < 12) comb[1024 + tid] = ta[(size_t)r * 12 + tid];
    __syncthreads();

    // ---- f1 = gelu(comb @ w1^T + b1) ----
    float acc = b1[tid];
    {
        const float* wr = w1 + (size_t)tid * 1036;
        for (int k = 0; k < 1036; k += 4) {
            float4 wv = *(const float4*)(wr + k);
            float4 cv = *(const float4*)(comb + k);
            acc += wv.x * cv.x + wv.y * cv.y + wv.z * cv.z + wv.w * cv.w;
        }
    }
    float f1 = gelu_exact(acc);

    // ---- LN(f1) ----
    s = f1; sq = f1 * f1;
#pragma unroll
    for (int o = 32; o; o >>= 1) { s += __shfl_xor(s, o, 64); sq += __shfl_xor(sq, o, 64); }
    if ((tid & 63) == 0) { rs_[tid >> 6] = s; rq_[tid >> 6] = sq; }
    __syncthreads();
    s = rs_[0] + rs_[1] + rs_[2] + rs_[3];
    sq = rq_[0] + rq_[1] + rq_[2] + rq_[3];
    m = s * (1.f / 256.f);
    var = sq * (1.f / 256.f) - m * m;
    rstd = 1.f / sqrtf(var + LN_EPS);
    fbuf[tid] = (f1 - m) * rstd * lng[tid] + lnb[tid];
    __syncthreads();

    // ---- f2 = fbuf @ w2^T + b2 ----
    acc = b2[tid];
    {
        const float* wr = w2 + (size_t)tid * 256;
        for (int k = 0; k < 256; k += 4) {
            float4 wv = *(const float4*)(wr + k);
            float4 cv = *(const float4*)(fbuf + k);
            acc += wv.x * cv.x + wv.y * cv.y + wv.z * cv.z + wv.w * cv.w;
        }
    }
    __syncthreads();
    comb[tid] = acc;     // f2 lives in comb[0..255]
    __syncthreads();

    // ---- c1 = gelu(f2 @ cw1^T + cb1), 128 ----
    if (tid < 128) {
        float a = cb1[tid];
        const float* wr = cw1 + (size_t)tid * 256;
        for (int k = 0; k < 256; k += 4) {
            float4 wv = *(const float4*)(wr + k);
            float4 cv = *(const float4*)(comb + k);
            a += wv.x * cv.x + wv.y * cv.y + wv.z * cv.z + wv.w * cv.w;
        }
        fbuf[tid] = gelu_exact(a);
    }
    __syncthreads();

    // ---- c2 = gelu(c1 @ cw2^T + cb2), 64 ----
    float c2v = 0.f;
    if (tid < 64) {
        float a = cb2[tid];
        const float* wr = cw2 + (size_t)tid * 128;
        for (int k = 0; k < 128; k += 4) {
            float4 wv = *(const float4*)(wr + k);
            float4 cv = *(const float4*)(fbuf + k);
            a += wv.x * cv.x + wv.y * cv.y + wv.z * cv.z + wv.w * cv.w;
        }
        c2v = gelu_exact(a);
    }
    __syncthreads();
    if (tid < 64) comb[tid] = c2v;
    __syncthreads();

    // ---- logits ----
    if (tid < 3) {
        float a = cb3[tid];
        const float* wr = cw3 + (size_t)tid * 64;
        for (int k = 0; k < 64; k++) a += wr[k] * comb[k];
        out[(size_t)r * 3 + tid] = a;
    }
}

// ---------------------------------------------------------------------------
extern "C" void kernel_launch(void* const* d_in, const int* in_sizes, int n_in,
                              void* d_out, int out_size, void* d_ws, size_t ws_size,
                              hipStream_t stream) {
    const float* x    = (const float*)d_in[0];
    const float* sent = (const float*)d_in[1];
    const float* ta   = (const float*)d_in[2];
    const float* ipw  = (const float*)d_in[3];
    const float* ipb  = (const float*)d_in[4];
    const float* inw  = (const float*)d_in[5];
    const float* cw   = (const float*)d_in[6];
    const float* cb   = (const float*)d_in[7];
    const float* xpw  = (const float*)d_in[8];
    const float* dtw  = (const float*)d_in[9];
    const float* dtb  = (const float*)d_in[10];
    const float* alog = (const float*)d_in[11];
    const float* Dp   = (const float*)d_in[12];
    const float* opw  = (const float*)d_in[13];
    const float* lng  = (const float*)d_in[14];
    const float* lnb  = (const float*)d_in[15];
    const float* eng  = (const float*)d_in[16];
    const float* enb  = (const float*)d_in[17];
    const float* fw1  = (const float*)d_in[18];
    const float* fb1  = (const float*)d_in[19];
    const float* flg  = (const float*)d_in[20];
    const float* flb  = (const float*)d_in[21];
    const float* fw2  = (const float*)d_in[22];
    const float* fb2  = (const float*)d_in[23];
    const float* cw1  = (const float*)d_in[24];
    const float* cb1  = (const float*)d_in[25];
    const float* cw2  = (const float*)d_in[26];
    const float* cb2  = (const float*)d_in[27];
    const float* cw3  = (const float*)d_in[28];
    const float* cb3  = (const float*)d_in[29];
    float* out = (float*)d_out;

    // --- split-bf16 weight buffers (persistent across layers, refilled each
    //     launch).  elements: in 4*262144, dt 4*262144, op 4*131072, x2 (hi/lo)
    unsigned short* wbf = (unsigned short*)d_ws;
    const size_t OFF_IN_HI = 0,       OFF_IN_LO = 1048576;
    const size_t OFF_DT_HI = 2097152, OFF_DT_LO = 3145728;
    const size_t OFF_OP_HI = 4194304, OFF_OP_LO = 4718592;
    const size_t WBF_TOTAL = 5242880;            // bf16 elems = 10.5 MB
    float* fbase = (float*)(wbf + WBF_TOTAL);

    // --- workspace: weights + h (BL*256) + chunk temporaries:
    //     xz R*1024 + xc R*512 + bc R*32 = R*1568
    //   + P,Q,Hin: 3 * SEG * nb*512*16 = nb*393216 floats.
    int c = 1;
    while (c < 32 &&
           (WBF_TOTAL / 2 + (size_t)BL * 256 + ((size_t)BL / c) * 1568 +
            (size_t)(B_SZ / c) * 393216) * sizeof(float) > ws_size)
        c <<= 1;
    const size_t R = BL / c;        // rows per chunk (multiple of L_SEQ)
    const int nb = B_SZ / c;        // batches per chunk
    const int Nseg = nb * 512 * 16; // (b,d,n) states per chunk

    float* hbuf  = fbase;                      // BL*256 (persistent)
    float* xzbuf = hbuf + (size_t)BL * 256;    // R*1024
    float* xcbuf = xzbuf + R * 1024;           // R*512
    float* bcbuf = xcbuf + R * 512;            // R*32
    float* Pbuf  = bcbuf + R * 32;             // SEG*Nseg
    float* Qbuf  = Pbuf + (size_t)SEG * Nseg;  // SEG*Nseg
    float* Hin   = Qbuf + (size_t)SEG * Nseg;  // SEG*Nseg

    // --- pre-split all weights to bf16 hi/lo (all 4 layers at once)
    convert_w_kernel<<<4096, 256, 0, stream>>>(inw, wbf + OFF_IN_HI, wbf + OFF_IN_LO, 1048576);
    convert_w_kernel<<<4096, 256, 0, stream>>>(dtw, wbf + OFF_DT_HI, wbf + OFF_DT_LO, 1048576);
    convert_w_kernel<<<2048, 256, 0, stream>>>(opw, wbf + OFF_OP_HI, wbf + OFF_OP_LO, 524288);

    input_proj_kernel<<<BL, 256, 0, stream>>>(x, ipw, ipb, hbuf);

    for (int l = 0; l < 4; l++) {
        const float* cw_l  = cw  + (size_t)l * 512 * 4;
        const float* cb_l  = cb  + (size_t)l * 512;
        const float* xpw_l = xpw + (size_t)l * 32 * 512;
        const float* dtb_l = dtb + (size_t)l * 512;
        const float* al_l  = alog + (size_t)l * 512 * 16;
        const float* Dp_l  = Dp  + (size_t)l * 512;
        const float* lng_l = lng + (size_t)l * 256;
        const float* lnb_l = lnb + (size_t)l * 256;
        const unsigned short* wih = wbf + OFF_IN_HI + (size_t)l * 262144;
        const unsigned short* wil = wbf + OFF_IN_LO + (size_t)l * 262144;
        const unsigned short* wdh = wbf + OFF_DT_HI + (size_t)l * 262144;
        const unsigned short* wdl = wbf + OFF_DT_LO + (size_t)l * 262144;
        const unsigned short* woh = wbf + OFF_OP_HI + (size_t)l * 131072;
        const unsigned short* wol = wbf + OFF_OP_LO + (size_t)l * 131072;

        for (int k = 0; k < c; k++) {
            float* hck = hbuf + (size_t)k * R * 256;

            // xz = h @ Wi^T            (R x 1024)
            gemm_bf16s<0><<<dim3(8, R / 128), 256, 0, stream>>>(
                hck, 256, wih, wil, nullptr, nullptr, xzbuf, 1024, (int)R, 1024, 256);
            // xc = silu(causal dwconv(xp) + cb)
            conv_silu_kernel<<<(unsigned)(R * 2), 256, 0, stream>>>(
                xzbuf, cw_l, cb_l, xcbuf);
            // dt = softplus(xc @ Wdt^T + bdt)  -> xz cols 0..511 (xp is dead)
            gemm_bf16s<1><<<dim3(4, R / 128), 256, 0, stream>>>(
                xcbuf, 512, wdh, wdl, dtb_l, nullptr, xzbuf, 1024, (int)R, 512, 512);
            // bc = xc @ Wx^T            (R x 32)
            xproj_kernel<<<(unsigned)(R / 8), 256, 0, stream>>>(xcbuf, xpw_l, bcbuf);
            // segment-parallel selective scan + gate (in-place over dt half)
            scan_pass1_kernel<<<(unsigned)(nb * 8 * SEG), 256, 0, stream>>>(
                xzbuf, xcbuf, bcbuf, al_l, Pbuf, Qbuf, nb);
            scan_pass2_kernel<<<(unsigned)(Nseg / 256), 256, 0, stream>>>(
                Pbuf, Qbuf, Hin, Nseg);
            scan_pass3_kernel<<<(unsigned)(nb * 8 * SEG), 256, 0, stream>>>(
                xzbuf, xcbuf, bcbuf, al_l, Dp_l, Hin, nb);
            // h += y @ Wo^T  (in-place residual), then LN in-place
            gemm_bf16s<2><<<dim3(2, R / 128), 256, 0, stream>>>(
                xzbuf, 1024, woh, wol, nullptr, hck, hck, 256, (int)R, 256, 512);
            ln256_kernel<<<(unsigned)(R / 4), 256, 0, stream>>>(
                hck, lng_l, lnb_l, hck);
        }
    }

    head_kernel<<<32, 256, 0, stream>>>(hbuf, sent, ta, eng, enb,
                                        fw1, fb1, flg, flb, fw2, fb2,
                                        cw1, cb1, cw2, cb2, cw3, cb3, out);
}

// Round 7
// 5513.844 us; speedup vs baseline: 3.3806x; 1.3404x over previous
//
#include <hip/hip_runtime.h>
#include <hip/hip_bf16.h>
#include <math.h>

// Dims
#define B_SZ   32
#define L_SEQ  2048
#define BL     (B_SZ * L_SEQ)        // 65536
#define D_MODEL 256
#define D_INNER 512
#define D_STATE 16
#define D_CONV  4
#define LN_EPS  1e-5f
#define SEG    16                    // segments per sequence (parallel scan)
#define TSEG   (L_SEQ / SEG)         // 128 steps per segment

typedef short  s16x8 __attribute__((ext_vector_type(8)));   // 8 bf16 (4 VGPRs)
typedef float  f32x4 __attribute__((ext_vector_type(4)));

// float -> bf16 (RNE), as raw ushort
__device__ __forceinline__ unsigned short f2bf(float x) {
    unsigned int u = __float_as_uint(x);
    unsigned int r = (u + 0x7fffu + ((u >> 16) & 1u)) >> 16;
    return (unsigned short)r;
}
__device__ __forceinline__ float bf2f(unsigned short h) {
    return __uint_as_float((unsigned int)h << 16);
}

// ---------------------------------------------------------------------------
// weight pre-convert: fp32 -> (hi, lo) bf16 pair.  a ~= hi + lo, err ~2^-18.
// ---------------------------------------------------------------------------
__global__ __launch_bounds__(256) void convert_w_kernel(
    const float* __restrict__ src, unsigned short* __restrict__ hi,
    unsigned short* __restrict__ lo, int n)
{
    int i = blockIdx.x * 256 + threadIdx.x;
    if (i < n) {
        float x = src[i];
        unsigned short h = f2bf(x);
        hi[i] = h;
        lo[i] = f2bf(x - bf2f(h));
    }
}

// ---------------------------------------------------------------------------
// input projection: h[row, c] = b[c] + sum_k x[row,k]*W[c,k]   (K=6)
// ---------------------------------------------------------------------------
__global__ __launch_bounds__(256) void input_proj_kernel(
    const float* __restrict__ x, const float* __restrict__ W,
    const float* __restrict__ b, float* __restrict__ h)
{
    size_t row = blockIdx.x;
    int c = threadIdx.x;
    const float* xr = x + row * 6;
    const float* wr = W + c * 6;
    float acc = b[c];
#pragma unroll
    for (int k = 0; k < 6; k++) acc += xr[k] * wr[k];
    h[row * D_MODEL + c] = acc;
}

// ---------------------------------------------------------------------------
// split-bf16 MFMA GEMM:  C[M,N] = A[M,K] @ W[N,K]^T (+ epilogue)
// A fp32 (converted to hi/lo bf16 during LDS staging); W pre-split hi/lo bf16.
// Each product = Ahi*Bhi + Ahi*Blo + Alo*Bhi  (3 MFMA) -> ~fp32 precision.
// 128x128 tile, BK=32, 256 thr = 4 waves (2x2 of 64x64), 16x16x32 MFMA.
// LDS k-stride 40 (80B rows): fragment ds_read_b128 2-way conflict = free.
// EPI 0: none, 1: softplus(acc+bias[n]), 2: acc + res (res==C in-place ok)
// ---------------------------------------------------------------------------
#define LDK 40
template <int EPI>
__global__ __launch_bounds__(256) void gemm_bf16s(
    const float* __restrict__ A, int lda,
    const unsigned short* __restrict__ Whi, const unsigned short* __restrict__ Wlo,
    const float* __restrict__ bias, const float* __restrict__ res,
    float* __restrict__ C, int ldc, int M, int N, int K)
{
    __shared__ unsigned short Ah[128 * LDK], Al[128 * LDK];
    __shared__ unsigned short Bh[128 * LDK], Bl[128 * LDK];
    const int tid = threadIdx.x;
    const int m0 = blockIdx.y * 128, n0 = blockIdx.x * 128;
    const int lane = tid & 63, wave = tid >> 6;
    const int quad = lane >> 4, l15 = lane & 15;
    const int wm = wave & 1, wn = wave >> 1;

    f32x4 acc[4][4];
#pragma unroll
    for (int mi = 0; mi < 4; mi++)
#pragma unroll
        for (int ni = 0; ni < 4; ni++) acc[mi][ni] = (f32x4){0.f, 0.f, 0.f, 0.f};

    for (int k0 = 0; k0 < K; k0 += 32) {
        // ---- stage: 128 rows x 32 k.  1024 groups of 4 elements.
#pragma unroll
        for (int i = 0; i < 4; i++) {
            int idx = i * 256 + tid;
            int row = idx >> 3, kq = (idx & 7) << 2;
            float4 v = *(const float4*)(A + (size_t)(m0 + row) * lda + k0 + kq);
            ushort4 h4, l4;
            h4.x = f2bf(v.x); l4.x = f2bf(v.x - bf2f(h4.x));
            h4.y = f2bf(v.y); l4.y = f2bf(v.y - bf2f(h4.y));
            h4.z = f2bf(v.z); l4.z = f2bf(v.z - bf2f(h4.z));
            h4.w = f2bf(v.w); l4.w = f2bf(v.w - bf2f(h4.w));
            *(ushort4*)&Ah[row * LDK + kq] = h4;
            *(ushort4*)&Al[row * LDK + kq] = l4;
            ushort4 wh = *(const ushort4*)(Whi + (size_t)(n0 + row) * K + k0 + kq);
            ushort4 wl = *(const ushort4*)(Wlo + (size_t)(n0 + row) * K + k0 + kq);
            *(ushort4*)&Bh[row * LDK + kq] = wh;
            *(ushort4*)&Bl[row * LDK + kq] = wl;
        }
        __syncthreads();

        // ---- fragments: lane holds X[m=l15][k=quad*8+j]
        s16x8 ah[4], al[4], bh[4], bl[4];
#pragma unroll
        for (int i = 0; i < 4; i++) {
            ah[i] = *(s16x8*)&Ah[(wm * 64 + i * 16 + l15) * LDK + quad * 8];
            al[i] = *(s16x8*)&Al[(wm * 64 + i * 16 + l15) * LDK + quad * 8];
            bh[i] = *(s16x8*)&Bh[(wn * 64 + i * 16 + l15) * LDK + quad * 8];
            bl[i] = *(s16x8*)&Bl[(wn * 64 + i * 16 + l15) * LDK + quad * 8];
        }
#pragma unroll
        for (int mi = 0; mi < 4; mi++)
#pragma unroll
            for (int ni = 0; ni < 4; ni++) {
                acc[mi][ni] = __builtin_amdgcn_mfma_f32_16x16x32_bf16(
                    ah[mi], bh[ni], acc[mi][ni], 0, 0, 0);
                acc[mi][ni] = __builtin_amdgcn_mfma_f32_16x16x32_bf16(
                    ah[mi], bl[ni], acc[mi][ni], 0, 0, 0);
                acc[mi][ni] = __builtin_amdgcn_mfma_f32_16x16x32_bf16(
                    al[mi], bh[ni], acc[mi][ni], 0, 0, 0);
            }
        __syncthreads();
    }

    // ---- epilogue: D row = quad*4 + reg, col = l15
#pragma unroll
    for (int mi = 0; mi < 4; mi++) {
        const int mrow = m0 + wm * 64 + mi * 16 + quad * 4;
#pragma unroll
        for (int ni = 0; ni < 4; ni++) {
            const int ncol = n0 + wn * 64 + ni * 16 + l15;
#pragma unroll
            for (int r = 0; r < 4; r++) {
                float v = acc[mi][ni][r];
                if (EPI == 1) {
                    v += bias[ncol];
                    v = (v > 20.f) ? v : log1pf(expf(v));
                } else if (EPI == 2) {
                    v += res[(size_t)(mrow + r) * ldc + ncol];
                }
                C[(size_t)(mrow + r) * ldc + ncol] = v;
            }
        }
    }
}

// ---------------------------------------------------------------------------
// xproj via split-bf16 MFMA: bc[R,32] = xc[R,512] @ Wx[32,512]^T.
// (round-6 xproj_kernel was vmem-issue bound: 144us/dispatch, VALU 7.5%,
//  HBM 1.6% — redundant per-lane row reads + serial dot chain.)
// Tile 64 rows x 32 cols, BK=32; 4 waves, each owns a 16-row m-tile x 2 n-tiles.
// ---------------------------------------------------------------------------
__global__ __launch_bounds__(256) void xproj_mfma_kernel(
    const float* __restrict__ xc,            // (R,512)
    const unsigned short* __restrict__ Whi,  // (32,512) bf16 hi
    const unsigned short* __restrict__ Wlo,  // (32,512) bf16 lo
    float* __restrict__ bc)                  // (R,32)
{
    __shared__ unsigned short Ah[64 * LDK], Al[64 * LDK];
    __shared__ unsigned short Bh[32 * LDK], Bl[32 * LDK];
    const int tid = threadIdx.x;
    const int m0 = blockIdx.x * 64;
    const int lane = tid & 63, wave = tid >> 6;
    const int quad = lane >> 4, l15 = lane & 15;

    f32x4 acc[2];
    acc[0] = (f32x4){0.f, 0.f, 0.f, 0.f};
    acc[1] = (f32x4){0.f, 0.f, 0.f, 0.f};

    for (int k0 = 0; k0 < 512; k0 += 32) {
        // stage A: 64 rows x 32 k = 2048 floats; 512 groups of 4 -> 2/thread
#pragma unroll
        for (int i = 0; i < 2; i++) {
            int idx = i * 256 + tid;
            int row = idx >> 3, kq = (idx & 7) << 2;
            float4 v = *(const float4*)(xc + (size_t)(m0 + row) * 512 + k0 + kq);
            ushort4 h4, l4;
            h4.x = f2bf(v.x); l4.x = f2bf(v.x - bf2f(h4.x));
            h4.y = f2bf(v.y); l4.y = f2bf(v.y - bf2f(h4.y));
            h4.z = f2bf(v.z); l4.z = f2bf(v.z - bf2f(h4.z));
            h4.w = f2bf(v.w); l4.w = f2bf(v.w - bf2f(h4.w));
            *(ushort4*)&Ah[row * LDK + kq] = h4;
            *(ushort4*)&Al[row * LDK + kq] = l4;
        }
        // stage B: 32 rows x 32 k = 1024 shorts; 256 groups of 4 -> 1/thread
        {
            int row = tid >> 3, kq = (tid & 7) << 2;
            *(ushort4*)&Bh[row * LDK + kq] =
                *(const ushort4*)(Whi + (size_t)row * 512 + k0 + kq);
            *(ushort4*)&Bl[row * LDK + kq] =
                *(const ushort4*)(Wlo + (size_t)row * 512 + k0 + kq);
        }
        __syncthreads();

        s16x8 ah = *(s16x8*)&Ah[(wave * 16 + l15) * LDK + quad * 8];
        s16x8 al = *(s16x8*)&Al[(wave * 16 + l15) * LDK + quad * 8];
#pragma unroll
        for (int ni = 0; ni < 2; ni++) {
            s16x8 bh = *(s16x8*)&Bh[(ni * 16 + l15) * LDK + quad * 8];
            s16x8 bl = *(s16x8*)&Bl[(ni * 16 + l15) * LDK + quad * 8];
            acc[ni] = __builtin_amdgcn_mfma_f32_16x16x32_bf16(ah, bh, acc[ni], 0, 0, 0);
            acc[ni] = __builtin_amdgcn_mfma_f32_16x16x32_bf16(ah, bl, acc[ni], 0, 0, 0);
            acc[ni] = __builtin_amdgcn_mfma_f32_16x16x32_bf16(al, bh, acc[ni], 0, 0, 0);
        }
        __syncthreads();
    }

#pragma unroll
    for (int ni = 0; ni < 2; ni++) {
        const int ncol = ni * 16 + l15;
#pragma unroll
        for (int r = 0; r < 4; r++) {
            const int mrow = m0 + wave * 16 + quad * 4 + r;
            bc[(size_t)mrow * 32 + ncol] = acc[ni][r];
        }
    }
}

// ---------------------------------------------------------------------------
// causal depthwise conv (k=4, left pad 3) + SiLU, over R rows (whole batches).
// xz: (R,1024), xp = cols 0..511.  xc out: (R,512)
// ---------------------------------------------------------------------------
__global__ __launch_bounds__(256) void conv_silu_kernel(
    const float* __restrict__ xz, const float* __restrict__ cw,
    const float* __restrict__ cb, float* __restrict__ xc)
{
    size_t idx = (size_t)blockIdx.x * 256 + threadIdx.x;  // over R*512
    int d = (int)(idx & 511);
    int row = (int)(idx >> 9);
    int t = row & (L_SEQ - 1);
    float4 w = *(const float4*)(cw + d * 4);
    float acc = cb[d];
    if (t >= 3) {
        const float* xp = xz + (size_t)row * 1024 + d;
        acc += xp[-3 * 1024] * w.x + xp[-2 * 1024] * w.y +
               xp[-1 * 1024] * w.z + xp[0] * w.w;
    } else {
        const float wj[4] = {w.x, w.y, w.z, w.w};
#pragma unroll
        for (int j = 0; j < 4; j++) {
            int tj = t + j - 3;
            if (tj >= 0) acc += xz[(size_t)(row + j - 3) * 1024 + d] * wj[j];
        }
    }
    float sig = 1.f / (1.f + __expf(-acc));
    xc[idx] = acc * sig;
}

// ---------------------------------------------------------------------------
// Segment-parallel selective scan, 4 states per lane.
// Lane = (d, nq): owns n = 4nq..4nq+3 in registers.  Block 256 thr = 64 d's.
// grid pass1/3: blockIdx = ((b*8)+g)*SEG + s, g covers d in [64g, 64g+64).
// ---------------------------------------------------------------------------
__global__ __launch_bounds__(256) void scan_pass1_kernel(
    const float* __restrict__ xzdt,   // (R,1024): dt in cols 0..511
    const float* __restrict__ xc,     // (R,512)
    const float* __restrict__ bc,     // (R,32): B=0..15
    const float* __restrict__ A_log,  // (512,16)
    float* __restrict__ Pbuf,         // [SEG][nb*512*16]
    float* __restrict__ Qbuf,
    int nb)
{
    const int tid = threadIdx.x;
    const int dl = tid >> 2, nq = tid & 3;
    const int s = blockIdx.x & (SEG - 1);
    const int g = (blockIdx.x >> 4) & 7;
    const int b = blockIdx.x >> 7;
    const int d = g * 64 + dl;

    float4 Av = *(const float4*)(A_log + d * 16 + nq * 4);
    const float A0 = -__expf(Av.x), A1 = -__expf(Av.y);
    const float A2 = -__expf(Av.z), A3 = -__expf(Av.w);

    const size_t row0 = (size_t)b * L_SEQ + (size_t)s * TSEG;
    const float* dtp = xzdt + row0 * 1024 + d;
    const float* xcp = xc + row0 * 512 + d;
    const float* bp  = bc + row0 * 32 + nq * 4;

    float h0 = 0.f, h1 = 0.f, h2 = 0.f, h3 = 0.f;
    float P0 = 1.f, P1 = 1.f, P2 = 1.f, P3 = 1.f;
#pragma unroll 4
    for (int t = 0; t < TSEG; t++) {
        const float dt = dtp[(size_t)t * 1024];
        const float xcv = xcp[(size_t)t * 512];
        const float4 Bv = *(const float4*)(bp + (size_t)t * 32);
        const float dtxc = dt * xcv;
        const float e0 = __expf(A0 * dt), e1 = __expf(A1 * dt);
        const float e2 = __expf(A2 * dt), e3 = __expf(A3 * dt);
        h0 = fmaf(e0, h0, dtxc * Bv.x); P0 *= e0;
        h1 = fmaf(e1, h1, dtxc * Bv.y); P1 *= e1;
        h2 = fmaf(e2, h2, dtxc * Bv.z); P2 *= e2;
        h3 = fmaf(e3, h3, dtxc * Bv.w); P3 *= e3;
    }
    const int N = nb * 512 * 16;
    const int idx = (b * 512 + d) * 16 + nq * 4;
    *(float4*)(Pbuf + (size_t)s * N + idx) = make_float4(P0, P1, P2, P3);
    *(float4*)(Qbuf + (size_t)s * N + idx) = make_float4(h0, h1, h2, h3);
}

__global__ __launch_bounds__(256) void scan_pass2_kernel(
    const float* __restrict__ Pbuf, const float* __restrict__ Qbuf,
    float* __restrict__ Hin, int N)
{
    const int idx = blockIdx.x * 256 + threadIdx.x;
    float run = 0.f;
#pragma unroll
    for (int s = 0; s < SEG; s++) {
        Hin[(size_t)s * N + idx] = run;
        run = fmaf(Pbuf[(size_t)s * N + idx], run, Qbuf[(size_t)s * N + idx]);
    }
}

__global__ __launch_bounds__(256) void scan_pass3_kernel(
    float* xzdt,                      // (R,1024): dt -> gated y, z in 512..1023
    const float* __restrict__ xc,     // (R,512)
    const float* __restrict__ bc,     // (R,32): B=0..15, C=16..31
    const float* __restrict__ A_log,  // (512,16)
    const float* __restrict__ Dp,     // (512)
    const float* __restrict__ Hin,    // [SEG][nb*512*16]
    int nb)
{
    const int tid = threadIdx.x;
    const int dl = tid >> 2, nq = tid & 3;
    const int s = blockIdx.x & (SEG - 1);
    const int g = (blockIdx.x >> 4) & 7;
    const int b = blockIdx.x >> 7;
    const int d = g * 64 + dl;

    float4 Av = *(const float4*)(A_log + d * 16 + nq * 4);
    const float A0 = -__expf(Av.x), A1 = -__expf(Av.y);
    const float A2 = -__expf(Av.z), A3 = -__expf(Av.w);
    const float Dd = Dp[d];

    const int N = nb * 512 * 16;
    const int idx = (b * 512 + d) * 16 + nq * 4;
    float4 h4 = *(const float4*)(Hin + (size_t)s * N + idx);
    float h0 = h4.x, h1 = h4.y, h2 = h4.z, h3 = h4.w;

    const size_t row0 = (size_t)b * L_SEQ + (size_t)s * TSEG;
    float* dtp = xzdt + row0 * 1024 + d;
    const float* zp = xzdt + row0 * 1024 + 512 + d;
    const float* xcp = xc + row0 * 512 + d;
    const float* bp  = bc + row0 * 32 + nq * 4;

#pragma unroll 4
    for (int t = 0; t < TSEG; t++) {
        const float dt = dtp[(size_t)t * 1024];
        const float xcv = xcp[(size_t)t * 512];
        const float zv  = zp[(size_t)t * 1024];
        const float4 Bv = *(const float4*)(bp + (size_t)t * 32);
        const float4 Cv = *(const float4*)(bp + (size_t)t * 32 + 16);
        const float dtxc = dt * xcv;
        const float e0 = __expf(A0 * dt), e1 = __expf(A1 * dt);
        const float e2 = __expf(A2 * dt), e3 = __expf(A3 * dt);
        h0 = fmaf(e0, h0, dtxc * Bv.x);
        h1 = fmaf(e1, h1, dtxc * Bv.y);
        h2 = fmaf(e2, h2, dtxc * Bv.z);
        h3 = fmaf(e3, h3, dtxc * Bv.w);
        float pv = h0 * Cv.x + h1 * Cv.y + h2 * Cv.z + h3 * Cv.w;
        pv += __shfl_xor(pv, 1, 4);
        pv += __shfl_xor(pv, 2, 4);
        if (nq == 0) {
            const float sig = 1.f / (1.f + __expf(-zv));
            dtp[(size_t)t * 1024] = (pv + xcv * Dd) * (zv * sig);
        }
    }
}

// ---------------------------------------------------------------------------
// LayerNorm over 256 cols, in-place safe; one wave per row, 4 rows per block
// ---------------------------------------------------------------------------
__global__ __launch_bounds__(256) void ln256_kernel(
    const float* __restrict__ in, const float* __restrict__ g,
    const float* __restrict__ b, float* __restrict__ out)
{
    int wave = threadIdx.x >> 6, lane = threadIdx.x & 63;
    size_t row = (size_t)blockIdx.x * 4 + wave;
    const float* p = in + row * 256 + lane * 4;
    float4 v = *(const float4*)p;
    float s = v.x + v.y + v.z + v.w;
    float sq = v.x * v.x + v.y * v.y + v.z * v.z + v.w * v.w;
#pragma unroll
    for (int o = 32; o; o >>= 1) {
        s += __shfl_xor(s, o, 64);
        sq += __shfl_xor(sq, o, 64);
    }
    float m = s * (1.f / 256.f);
    float var = sq * (1.f / 256.f) - m * m;
    float rs = 1.f / sqrtf(var + LN_EPS);
    float4 gg = *(const float4*)(g + lane * 4);
    float4 bb = *(const float4*)(b + lane * 4);
    float4 o4;
    o4.x = (v.x - m) * rs * gg.x + bb.x;
    o4.y = (v.y - m) * rs * gg.y + bb.y;
    o4.z = (v.z - m) * rs * gg.z + bb.z;
    o4.w = (v.w - m) * rs * gg.w + bb.w;
    *(float4*)(out + row * 256 + lane * 4) = o4;
}

// ---------------------------------------------------------------------------
// head: tick-LN -> fusion (gelu, LN, linear) -> classifier.  1 block / batch row
// ---------------------------------------------------------------------------
__device__ __forceinline__ float gelu_exact(float x) {
    return 0.5f * x * (1.f + erff(x * 0.70710678118654752f));
}

__global__ __launch_bounds__(256) void head_kernel(
    const float* __restrict__ h, const float* __restrict__ sent,
    const float* __restrict__ ta,
    const float* __restrict__ eng, const float* __restrict__ enb,
    const float* __restrict__ w1, const float* __restrict__ b1,
    const float* __restrict__ lng, const float* __restrict__ lnb,
    const float* __restrict__ w2, const float* __restrict__ b2,
    const float* __restrict__ cw1, const float* __restrict__ cb1,
    const float* __restrict__ cw2, const float* __restrict__ cb2,
    const float* __restrict__ cw3, const float* __restrict__ cb3,
    float* __restrict__ out)
{
    __shared__ __align__(16) float comb[1036];
    __shared__ __align__(16) float fbuf[256];
    __shared__ float rs_[4], rq_[4];
    const int r = blockIdx.x, tid = threadIdx.x;

    // ---- tick = LN(h[:, L-1]) ----
    float v = h[((size_t)r * L_SEQ + (L_SEQ - 1)) * 256 + tid];
    float s = v, sq = v * v;
#pragma unroll
    for (int o = 32; o; o >>= 1) { s += __shfl_xor(s, o, 64); sq += __shfl_xor(sq, o, 64); }
    if ((tid & 63) == 0) { rs_[tid >> 6] = s; rq_[tid >> 6] = sq; }
    __syncthreads();
    s = rs_[0] + rs_[1] + rs_[2] + rs_[3];
    sq = rq_[0] + rq_[1] + rq_[2] + rq_[3];
    float m = s * (1.f / 256.f);
    float var = sq * (1.f / 256.f) - m * m;
    float rstd = 1.f / sqrtf(var + LN_EPS);
    comb[tid] = (v - m) * rstd * eng[tid] + enb[tid];
    comb[256 + tid] = sent[(size_t)r * 768 + tid];
    comb[512 + tid] = sent[(size_t)r * 768 + 256 + tid];
    comb[768 + tid] = sent[(size_t)r * 768 + 512 + tid];
    if (tid < 12) comb[1024 + tid] = ta[(size_t)r * 12 + tid];
    __syncthreads();

    // ---- f1 = gelu(comb @ w1^T + b1) ----
    float acc = b1[tid];
    {
        const float* wr = w1 + (size_t)tid * 1036;
        for (int k = 0; k < 1036; k += 4) {
            float4 wv = *(const float4*)(wr + k);
            float4 cv = *(const float4*)(comb + k);
            acc += wv.x * cv.x + wv.y * cv.y + wv.z * cv.z + wv.w * cv.w;
        }
    }
    float f1 = gelu_exact(acc);

    // ---- LN(f1) ----
    s = f1; sq = f1 * f1;
#pragma unroll
    for (int o = 32; o; o >>= 1) { s += __shfl_xor(s, o, 64); sq += __shfl_xor(sq, o, 64); }
    if ((tid & 63) == 0) { rs_[tid >> 6] = s; rq_[tid >> 6] = sq; }
    __syncthreads();
    s = rs_[0] + rs_[1] + rs_[2] + rs_[3];
    sq = rq_[0] + rq_[1] + rq_[2] + rq_[3];
    m = s * (1.f / 256.f);
    var = sq * (1.f / 256.f) - m * m;
    rstd = 1.f / sqrtf(var + LN_EPS);
    fbuf[tid] = (f1 - m) * rstd * lng[tid] + lnb[tid];
    __syncthreads();

    // ---- f2 = fbuf @ w2^T + b2 ----
    acc = b2[tid];
    {
        const float* wr = w2 + (size_t)tid * 256;
        for (int k = 0; k < 256; k += 4) {
            float4 wv = *(const float4*)(wr + k);
            float4 cv = *(const float4*)(fbuf + k);
            acc += wv.x * cv.x + wv.y * cv.y + wv.z * cv.z + wv.w * cv.w;
        }
    }
    __syncthreads();
    comb[tid] = acc;     // f2 lives in comb[0..255]
    __syncthreads();

    // ---- c1 = gelu(f2 @ cw1^T + cb1), 128 ----
    if (tid < 128) {
        float a = cb1[tid];
        const float* wr = cw1 + (size_t)tid * 256;
        for (int k = 0; k < 256; k += 4) {
            float4 wv = *(const float4*)(wr + k);
            float4 cv = *(const float4*)(comb + k);
            a += wv.x * cv.x + wv.y * cv.y + wv.z * cv.z + wv.w * cv.w;
        }
        fbuf[tid] = gelu_exact(a);
    }
    __syncthreads();

    // ---- c2 = gelu(c1 @ cw2^T + cb2), 64 ----
    float c2v = 0.f;
    if (tid < 64) {
        float a = cb2[tid];
        const float* wr = cw2 + (size_t)tid * 128;
        for (int k = 0; k < 128; k += 4) {
            float4 wv = *(const float4*)(wr + k);
            float4 cv = *(const float4*)(fbuf + k);
            a += wv.x * cv.x + wv.y * cv.y + wv.z * cv.z + wv.w * cv.w;
        }
        c2v = gelu_exact(a);
    }
    __syncthreads();
    if (tid < 64) comb[tid] = c2v;
    __syncthreads();

    // ---- logits ----
    if (tid < 3) {
        float a = cb3[tid];
        const float* wr = cw3 + (size_t)tid * 64;
        for (int k = 0; k < 64; k++) a += wr[k] * comb[k];
        out[(size_t)r * 3 + tid] = a;
    }
}

// ---------------------------------------------------------------------------
extern "C" void kernel_launch(void* const* d_in, const int* in_sizes, int n_in,
                              void* d_out, int out_size, void* d_ws, size_t ws_size,
                              hipStream_t stream) {
    const float* x    = (const float*)d_in[0];
    const float* sent = (const float*)d_in[1];
    const float* ta   = (const float*)d_in[2];
    const float* ipw  = (const float*)d_in[3];
    const float* ipb  = (const float*)d_in[4];
    const float* inw  = (const float*)d_in[5];
    const float* cw   = (const float*)d_in[6];
    const float* cb   = (const float*)d_in[7];
    const float* xpw  = (const float*)d_in[8];
    const float* dtw  = (const float*)d_in[9];
    const float* dtb  = (const float*)d_in[10];
    const float* alog = (const float*)d_in[11];
    const float* Dp   = (const float*)d_in[12];
    const float* opw  = (const float*)d_in[13];
    const float* lng  = (const float*)d_in[14];
    const float* lnb  = (const float*)d_in[15];
    const float* eng  = (const float*)d_in[16];
    const float* enb  = (const float*)d_in[17];
    const float* fw1  = (const float*)d_in[18];
    const float* fb1  = (const float*)d_in[19];
    const float* flg  = (const float*)d_in[20];
    const float* flb  = (const float*)d_in[21];
    const float* fw2  = (const float*)d_in[22];
    const float* fb2  = (const float*)d_in[23];
    const float* cw1  = (const float*)d_in[24];
    const float* cb1  = (const float*)d_in[25];
    const float* cw2  = (const float*)d_in[26];
    const float* cb2  = (const float*)d_in[27];
    const float* cw3  = (const float*)d_in[28];
    const float* cb3  = (const float*)d_in[29];
    float* out = (float*)d_out;

    // --- split-bf16 weight buffers.  elements (hi/lo each):
    //     in 4*262144, dt 4*262144, op 4*131072, xp 4*16384
    unsigned short* wbf = (unsigned short*)d_ws;
    const size_t OFF_IN_HI = 0,       OFF_IN_LO = 1048576;
    const size_t OFF_DT_HI = 2097152, OFF_DT_LO = 3145728;
    const size_t OFF_OP_HI = 4194304, OFF_OP_LO = 4718592;
    const size_t OFF_XP_HI = 5242880, OFF_XP_LO = 5308416;
    const size_t WBF_TOTAL = 5373952;            // bf16 elems = 10.75 MB
    float* fbase = (float*)(wbf + WBF_TOTAL);

    // --- workspace: weights + h (BL*256) + chunk temporaries:
    //     xz R*1024 + xc R*512 + bc R*32 = R*1568
    //   + P,Q,Hin: 3 * SEG * nb*512*16 = nb*393216 floats.
    int c = 1;
    while (c < 32 &&
           (WBF_TOTAL / 2 + (size_t)BL * 256 + ((size_t)BL / c) * 1568 +
            (size_t)(B_SZ / c) * 393216) * sizeof(float) > ws_size)
        c <<= 1;
    const size_t R = BL / c;        // rows per chunk (multiple of L_SEQ)
    const int nb = B_SZ / c;        // batches per chunk
    const int Nseg = nb * 512 * 16; // (b,d,n) states per chunk

    float* hbuf  = fbase;                      // BL*256 (persistent)
    float* xzbuf = hbuf + (size_t)BL * 256;    // R*1024
    float* xcbuf = xzbuf + R * 1024;           // R*512
    float* bcbuf = xcbuf + R * 512;            // R*32
    float* Pbuf  = bcbuf + R * 32;             // SEG*Nseg
    float* Qbuf  = Pbuf + (size_t)SEG * Nseg;  // SEG*Nseg
    float* Hin   = Qbuf + (size_t)SEG * Nseg;  // SEG*Nseg

    // --- pre-split all weights to bf16 hi/lo (all 4 layers at once)
    convert_w_kernel<<<4096, 256, 0, stream>>>(inw, wbf + OFF_IN_HI, wbf + OFF_IN_LO, 1048576);
    convert_w_kernel<<<4096, 256, 0, stream>>>(dtw, wbf + OFF_DT_HI, wbf + OFF_DT_LO, 1048576);
    convert_w_kernel<<<2048, 256, 0, stream>>>(opw, wbf + OFF_OP_HI, wbf + OFF_OP_LO, 524288);
    convert_w_kernel<<<256, 256, 0, stream>>>(xpw, wbf + OFF_XP_HI, wbf + OFF_XP_LO, 65536);

    input_proj_kernel<<<BL, 256, 0, stream>>>(x, ipw, ipb, hbuf);

    for (int l = 0; l < 4; l++) {
        const float* cw_l  = cw  + (size_t)l * 512 * 4;
        const float* cb_l  = cb  + (size_t)l * 512;
        const float* dtb_l = dtb + (size_t)l * 512;
        const float* al_l  = alog + (size_t)l * 512 * 16;
        const float* Dp_l  = Dp  + (size_t)l * 512;
        const float* lng_l = lng + (size_t)l * 256;
        const float* lnb_l = lnb + (size_t)l * 256;
        const unsigned short* wih = wbf + OFF_IN_HI + (size_t)l * 262144;
        const unsigned short* wil = wbf + OFF_IN_LO + (size_t)l * 262144;
        const unsigned short* wdh = wbf + OFF_DT_HI + (size_t)l * 262144;
        const unsigned short* wdl = wbf + OFF_DT_LO + (size_t)l * 262144;
        const unsigned short* woh = wbf + OFF_OP_HI + (size_t)l * 131072;
        const unsigned short* wol = wbf + OFF_OP_LO + (size_t)l * 131072;
        const unsigned short* wxh = wbf + OFF_XP_HI + (size_t)l * 16384;
        const unsigned short* wxl = wbf + OFF_XP_LO + (size_t)l * 16384;

        for (int k = 0; k < c; k++) {
            float* hck = hbuf + (size_t)k * R * 256;

            // xz = h @ Wi^T            (R x 1024)
            gemm_bf16s<0><<<dim3(8, R / 128), 256, 0, stream>>>(
                hck, 256, wih, wil, nullptr, nullptr, xzbuf, 1024, (int)R, 1024, 256);
            // xc = silu(causal dwconv(xp) + cb)
            conv_silu_kernel<<<(unsigned)(R * 2), 256, 0, stream>>>(
                xzbuf, cw_l, cb_l, xcbuf);
            // dt = softplus(xc @ Wdt^T + bdt)  -> xz cols 0..511 (xp is dead)
            gemm_bf16s<1><<<dim3(4, R / 128), 256, 0, stream>>>(
                xcbuf, 512, wdh, wdl, dtb_l, nullptr, xzbuf, 1024, (int)R, 512, 512);
            // bc = xc @ Wx^T            (R x 32), MFMA
            xproj_mfma_kernel<<<(unsigned)(R / 64), 256, 0, stream>>>(
                xcbuf, wxh, wxl, bcbuf);
            // segment-parallel selective scan + gate (in-place over dt half)
            scan_pass1_kernel<<<(unsigned)(nb * 8 * SEG), 256, 0, stream>>>(
                xzbuf, xcbuf, bcbuf, al_l, Pbuf, Qbuf, nb);
            scan_pass2_kernel<<<(unsigned)(Nseg / 256), 256, 0, stream>>>(
                Pbuf, Qbuf, Hin, Nseg);
            scan_pass3_kernel<<<(unsigned)(nb * 8 * SEG), 256, 0, stream>>>(
                xzbuf, xcbuf, bcbuf, al_l, Dp_l, Hin, nb);
            // h += y @ Wo^T  (in-place residual), then LN in-place
            gemm_bf16s<2><<<dim3(2, R / 128), 256, 0, stream>>>(
                xzbuf, 1024, woh, wol, nullptr, hck, hck, 256, (int)R, 256, 512);
            ln256_kernel<<<(unsigned)(R / 4), 256, 0, stream>>>(
                hck, lng_l, lnb_l, hck);
        }
    }

    head_kernel<<<32, 256, 0, stream>>>(hbuf, sent, ta, eng, enb,
                                        fw1, fb1, flg, flb, fw2, fb2,
                                        cw1, cb1, cw2, cb2, cw3, cb3, out);
}

// Round 8
// 4940.845 us; speedup vs baseline: 3.7726x; 1.1160x over previous
//
#include <hip/hip_runtime.h>
#include <hip/hip_bf16.h>
#include <math.h>

// Dims
#define B_SZ   32
#define L_SEQ  2048
#define BL     (B_SZ * L_SEQ)        // 65536
#define D_MODEL 256
#define D_INNER 512
#define D_STATE 16
#define D_CONV  4
#define LN_EPS  1e-5f
#define SEG    32                    // segments per sequence (parallel scan)
#define TSEG   (L_SEQ / SEG)         // 64 steps per segment

typedef short  s16x8 __attribute__((ext_vector_type(8)));   // 8 bf16 (4 VGPRs)
typedef float  f32x4 __attribute__((ext_vector_type(4)));

// float -> bf16 (RNE), as raw ushort
__device__ __forceinline__ unsigned short f2bf(float x) {
    unsigned int u = __float_as_uint(x);
    unsigned int r = (u + 0x7fffu + ((u >> 16) & 1u)) >> 16;
    return (unsigned short)r;
}
__device__ __forceinline__ float bf2f(unsigned short h) {
    return __uint_as_float((unsigned int)h << 16);
}

// ---------------------------------------------------------------------------
// weight pre-convert: fp32 -> (hi, lo) bf16 pair.  a ~= hi + lo, err ~2^-18.
// ---------------------------------------------------------------------------
__global__ __launch_bounds__(256) void convert_w_kernel(
    const float* __restrict__ src, unsigned short* __restrict__ hi,
    unsigned short* __restrict__ lo, int n)
{
    int i = blockIdx.x * 256 + threadIdx.x;
    if (i < n) {
        float x = src[i];
        unsigned short h = f2bf(x);
        hi[i] = h;
        lo[i] = f2bf(x - bf2f(h));
    }
}

// ---------------------------------------------------------------------------
// input projection: h[row, c] = b[c] + sum_k x[row,k]*W[c,k]   (K=6)
// ---------------------------------------------------------------------------
__global__ __launch_bounds__(256) void input_proj_kernel(
    const float* __restrict__ x, const float* __restrict__ W,
    const float* __restrict__ b, float* __restrict__ h)
{
    size_t row = blockIdx.x;
    int c = threadIdx.x;
    const float* xr = x + row * 6;
    const float* wr = W + c * 6;
    float acc = b[c];
#pragma unroll
    for (int k = 0; k < 6; k++) acc += xr[k] * wr[k];
    h[row * D_MODEL + c] = acc;
}

// ---------------------------------------------------------------------------
// split-bf16 MFMA GEMM:  C[M,N] = A[M,K] @ W[N,K]^T (+ epilogue)
// A fp32 (converted to hi/lo bf16 during LDS staging); W pre-split hi/lo bf16.
// Each product = Ahi*Bhi + Ahi*Blo + Alo*Bhi  (3 MFMA) -> ~fp32 precision.
// 128x128 tile, BK=32, 256 thr = 4 waves (2x2 of 64x64), 16x16x32 MFMA.
// LDS k-stride 40 (80B rows): fragment ds_read_b128 2-way conflict = free.
// EPI 0: none, 1: softplus(acc+bias[n]), 2: acc + res (res==C in-place ok)
// ---------------------------------------------------------------------------
#define LDK 40
template <int EPI>
__global__ __launch_bounds__(256) void gemm_bf16s(
    const float* __restrict__ A, int lda,
    const unsigned short* __restrict__ Whi, const unsigned short* __restrict__ Wlo,
    const float* __restrict__ bias, const float* __restrict__ res,
    float* __restrict__ C, int ldc, int M, int N, int K)
{
    __shared__ unsigned short Ah[128 * LDK], Al[128 * LDK];
    __shared__ unsigned short Bh[128 * LDK], Bl[128 * LDK];
    const int tid = threadIdx.x;
    const int m0 = blockIdx.y * 128, n0 = blockIdx.x * 128;
    const int lane = tid & 63, wave = tid >> 6;
    const int quad = lane >> 4, l15 = lane & 15;
    const int wm = wave & 1, wn = wave >> 1;

    f32x4 acc[4][4];
#pragma unroll
    for (int mi = 0; mi < 4; mi++)
#pragma unroll
        for (int ni = 0; ni < 4; ni++) acc[mi][ni] = (f32x4){0.f, 0.f, 0.f, 0.f};

    for (int k0 = 0; k0 < K; k0 += 32) {
        // ---- stage: 128 rows x 32 k.  1024 groups of 4 elements.
#pragma unroll
        for (int i = 0; i < 4; i++) {
            int idx = i * 256 + tid;
            int row = idx >> 3, kq = (idx & 7) << 2;
            float4 v = *(const float4*)(A + (size_t)(m0 + row) * lda + k0 + kq);
            ushort4 h4, l4;
            h4.x = f2bf(v.x); l4.x = f2bf(v.x - bf2f(h4.x));
            h4.y = f2bf(v.y); l4.y = f2bf(v.y - bf2f(h4.y));
            h4.z = f2bf(v.z); l4.z = f2bf(v.z - bf2f(h4.z));
            h4.w = f2bf(v.w); l4.w = f2bf(v.w - bf2f(h4.w));
            *(ushort4*)&Ah[row * LDK + kq] = h4;
            *(ushort4*)&Al[row * LDK + kq] = l4;
            ushort4 wh = *(const ushort4*)(Whi + (size_t)(n0 + row) * K + k0 + kq);
            ushort4 wl = *(const ushort4*)(Wlo + (size_t)(n0 + row) * K + k0 + kq);
            *(ushort4*)&Bh[row * LDK + kq] = wh;
            *(ushort4*)&Bl[row * LDK + kq] = wl;
        }
        __syncthreads();

        // ---- fragments: lane holds X[m=l15][k=quad*8+j]
        s16x8 ah[4], al[4], bh[4], bl[4];
#pragma unroll
        for (int i = 0; i < 4; i++) {
            ah[i] = *(s16x8*)&Ah[(wm * 64 + i * 16 + l15) * LDK + quad * 8];
            al[i] = *(s16x8*)&Al[(wm * 64 + i * 16 + l15) * LDK + quad * 8];
            bh[i] = *(s16x8*)&Bh[(wn * 64 + i * 16 + l15) * LDK + quad * 8];
            bl[i] = *(s16x8*)&Bl[(wn * 64 + i * 16 + l15) * LDK + quad * 8];
        }
#pragma unroll
        for (int mi = 0; mi < 4; mi++)
#pragma unroll
            for (int ni = 0; ni < 4; ni++) {
                acc[mi][ni] = __builtin_amdgcn_mfma_f32_16x16x32_bf16(
                    ah[mi], bh[ni], acc[mi][ni], 0, 0, 0);
                acc[mi][ni] = __builtin_amdgcn_mfma_f32_16x16x32_bf16(
                    ah[mi], bl[ni], acc[mi][ni], 0, 0, 0);
                acc[mi][ni] = __builtin_amdgcn_mfma_f32_16x16x32_bf16(
                    al[mi], bh[ni], acc[mi][ni], 0, 0, 0);
            }
        __syncthreads();
    }

    // ---- epilogue: D row = quad*4 + reg, col = l15
#pragma unroll
    for (int mi = 0; mi < 4; mi++) {
        const int mrow = m0 + wm * 64 + mi * 16 + quad * 4;
#pragma unroll
        for (int ni = 0; ni < 4; ni++) {
            const int ncol = n0 + wn * 64 + ni * 16 + l15;
#pragma unroll
            for (int r = 0; r < 4; r++) {
                float v = acc[mi][ni][r];
                if (EPI == 1) {
                    v += bias[ncol];
                    v = (v > 20.f) ? v : log1pf(expf(v));
                } else if (EPI == 2) {
                    v += res[(size_t)(mrow + r) * ldc + ncol];
                }
                C[(size_t)(mrow + r) * ldc + ncol] = v;
            }
        }
    }
}

// ---------------------------------------------------------------------------
// xproj via split-bf16 MFMA: bc[R,32] = xc[R,512] @ Wx[32,512]^T.
// Tile 64 rows x 32 cols, BK=32; 4 waves, each owns a 16-row m-tile x 2 n-tiles.
// ---------------------------------------------------------------------------
__global__ __launch_bounds__(256) void xproj_mfma_kernel(
    const float* __restrict__ xc,            // (R,512)
    const unsigned short* __restrict__ Whi,  // (32,512) bf16 hi
    const unsigned short* __restrict__ Wlo,  // (32,512) bf16 lo
    float* __restrict__ bc)                  // (R,32)
{
    __shared__ unsigned short Ah[64 * LDK], Al[64 * LDK];
    __shared__ unsigned short Bh[32 * LDK], Bl[32 * LDK];
    const int tid = threadIdx.x;
    const int m0 = blockIdx.x * 64;
    const int lane = tid & 63, wave = tid >> 6;
    const int quad = lane >> 4, l15 = lane & 15;

    f32x4 acc[2];
    acc[0] = (f32x4){0.f, 0.f, 0.f, 0.f};
    acc[1] = (f32x4){0.f, 0.f, 0.f, 0.f};

    for (int k0 = 0; k0 < 512; k0 += 32) {
        // stage A: 64 rows x 32 k = 2048 floats; 512 groups of 4 -> 2/thread
#pragma unroll
        for (int i = 0; i < 2; i++) {
            int idx = i * 256 + tid;
            int row = idx >> 3, kq = (idx & 7) << 2;
            float4 v = *(const float4*)(xc + (size_t)(m0 + row) * 512 + k0 + kq);
            ushort4 h4, l4;
            h4.x = f2bf(v.x); l4.x = f2bf(v.x - bf2f(h4.x));
            h4.y = f2bf(v.y); l4.y = f2bf(v.y - bf2f(h4.y));
            h4.z = f2bf(v.z); l4.z = f2bf(v.z - bf2f(h4.z));
            h4.w = f2bf(v.w); l4.w = f2bf(v.w - bf2f(h4.w));
            *(ushort4*)&Ah[row * LDK + kq] = h4;
            *(ushort4*)&Al[row * LDK + kq] = l4;
        }
        // stage B: 32 rows x 32 k = 1024 shorts; 256 groups of 4 -> 1/thread
        {
            int row = tid >> 3, kq = (tid & 7) << 2;
            *(ushort4*)&Bh[row * LDK + kq] =
                *(const ushort4*)(Whi + (size_t)row * 512 + k0 + kq);
            *(ushort4*)&Bl[row * LDK + kq] =
                *(const ushort4*)(Wlo + (size_t)row * 512 + k0 + kq);
        }
        __syncthreads();

        s16x8 ah = *(s16x8*)&Ah[(wave * 16 + l15) * LDK + quad * 8];
        s16x8 al = *(s16x8*)&Al[(wave * 16 + l15) * LDK + quad * 8];
#pragma unroll
        for (int ni = 0; ni < 2; ni++) {
            s16x8 bh = *(s16x8*)&Bh[(ni * 16 + l15) * LDK + quad * 8];
            s16x8 bl = *(s16x8*)&Bl[(ni * 16 + l15) * LDK + quad * 8];
            acc[ni] = __builtin_amdgcn_mfma_f32_16x16x32_bf16(ah, bh, acc[ni], 0, 0, 0);
            acc[ni] = __builtin_amdgcn_mfma_f32_16x16x32_bf16(ah, bl, acc[ni], 0, 0, 0);
            acc[ni] = __builtin_amdgcn_mfma_f32_16x16x32_bf16(al, bh, acc[ni], 0, 0, 0);
        }
        __syncthreads();
    }

#pragma unroll
    for (int ni = 0; ni < 2; ni++) {
        const int ncol = ni * 16 + l15;
#pragma unroll
        for (int r = 0; r < 4; r++) {
            const int mrow = m0 + wave * 16 + quad * 4 + r;
            bc[(size_t)mrow * 32 + ncol] = acc[ni][r];
        }
    }
}

// ---------------------------------------------------------------------------
// causal depthwise conv (k=4, left pad 3) + SiLU, vectorized x4 over d.
// (round-7: scalar version was vmem-issue bound; 4x fewer load/store issues.)
// xz: (R,1024), xp = cols 0..511.  xc out: (R,512).  Thread = (row, 4 d's).
// ---------------------------------------------------------------------------
__global__ __launch_bounds__(256) void conv_silu_kernel(
    const float* __restrict__ xz, const float* __restrict__ cw,
    const float* __restrict__ cb, float* __restrict__ xc)
{
    size_t idx = (size_t)blockIdx.x * 256 + threadIdx.x;  // over R*128
    const int d4 = (int)(idx & 127) << 2;
    const int row = (int)(idx >> 7);
    const int t = row & (L_SEQ - 1);

    const float4 wA = *(const float4*)(cw + (d4 + 0) * 4);
    const float4 wB = *(const float4*)(cw + (d4 + 1) * 4);
    const float4 wC = *(const float4*)(cw + (d4 + 2) * 4);
    const float4 wD = *(const float4*)(cw + (d4 + 3) * 4);
    const float4 bias4 = *(const float4*)(cb + d4);
    const float4 zero = make_float4(0.f, 0.f, 0.f, 0.f);

    const float* p = xz + (size_t)row * 1024 + d4;
    float4 x3 = *(const float4*)p;                                // tap t
    float4 x2 = (t >= 1) ? *(const float4*)(p - 1024) : zero;     // t-1
    float4 x1 = (t >= 2) ? *(const float4*)(p - 2048) : zero;     // t-2
    float4 x0 = (t >= 3) ? *(const float4*)(p - 3072) : zero;     // t-3

    float4 a;
    a.x = bias4.x + x0.x * wA.x + x1.x * wA.y + x2.x * wA.z + x3.x * wA.w;
    a.y = bias4.y + x0.y * wB.x + x1.y * wB.y + x2.y * wB.z + x3.y * wB.w;
    a.z = bias4.z + x0.z * wC.x + x1.z * wC.y + x2.z * wC.z + x3.z * wC.w;
    a.w = bias4.w + x0.w * wD.x + x1.w * wD.y + x2.w * wD.z + x3.w * wD.w;

    float4 o;
    o.x = a.x / (1.f + __expf(-a.x));
    o.y = a.y / (1.f + __expf(-a.y));
    o.z = a.z / (1.f + __expf(-a.z));
    o.w = a.w / (1.f + __expf(-a.w));
    *(float4*)(xc + (size_t)row * 512 + d4) = o;
}

// ---------------------------------------------------------------------------
// Segment-parallel selective scan, 4 states per lane.  SEG=32 segments
// (round-7 pass3: occupancy 41%, VALU 38% — double TLP to fill the CUs).
// Lane = (d, nq): owns n = 4nq..4nq+3 in registers.  Block 256 thr = 64 d's.
// grid pass1/3: blockIdx = ((b*8)+g)*SEG + s, g covers d in [64g, 64g+64).
// ---------------------------------------------------------------------------
__global__ __launch_bounds__(256) void scan_pass1_kernel(
    const float* __restrict__ xzdt,   // (R,1024): dt in cols 0..511
    const float* __restrict__ xc,     // (R,512)
    const float* __restrict__ bc,     // (R,32): B=0..15
    const float* __restrict__ A_log,  // (512,16)
    float* __restrict__ Pbuf,         // [SEG][nb*512*16]
    float* __restrict__ Qbuf,
    int nb)
{
    const int tid = threadIdx.x;
    const int dl = tid >> 2, nq = tid & 3;
    const int s = blockIdx.x & (SEG - 1);
    const int g = (blockIdx.x >> 5) & 7;
    const int b = blockIdx.x >> 8;
    const int d = g * 64 + dl;

    float4 Av = *(const float4*)(A_log + d * 16 + nq * 4);
    const float A0 = -__expf(Av.x), A1 = -__expf(Av.y);
    const float A2 = -__expf(Av.z), A3 = -__expf(Av.w);

    const size_t row0 = (size_t)b * L_SEQ + (size_t)s * TSEG;
    const float* dtp = xzdt + row0 * 1024 + d;
    const float* xcp = xc + row0 * 512 + d;
    const float* bp  = bc + row0 * 32 + nq * 4;

    float h0 = 0.f, h1 = 0.f, h2 = 0.f, h3 = 0.f;
    float P0 = 1.f, P1 = 1.f, P2 = 1.f, P3 = 1.f;
#pragma unroll 4
    for (int t = 0; t < TSEG; t++) {
        const float dt = dtp[(size_t)t * 1024];
        const float xcv = xcp[(size_t)t * 512];
        const float4 Bv = *(const float4*)(bp + (size_t)t * 32);
        const float dtxc = dt * xcv;
        const float e0 = __expf(A0 * dt), e1 = __expf(A1 * dt);
        const float e2 = __expf(A2 * dt), e3 = __expf(A3 * dt);
        h0 = fmaf(e0, h0, dtxc * Bv.x); P0 *= e0;
        h1 = fmaf(e1, h1, dtxc * Bv.y); P1 *= e1;
        h2 = fmaf(e2, h2, dtxc * Bv.z); P2 *= e2;
        h3 = fmaf(e3, h3, dtxc * Bv.w); P3 *= e3;
    }
    const int N = nb * 512 * 16;
    const int idx = (b * 512 + d) * 16 + nq * 4;
    *(float4*)(Pbuf + (size_t)s * N + idx) = make_float4(P0, P1, P2, P3);
    *(float4*)(Qbuf + (size_t)s * N + idx) = make_float4(h0, h1, h2, h3);
}

// pass2: combine segments sequentially; writes h_in IN-PLACE over Pbuf.
__global__ __launch_bounds__(256) void scan_pass2_kernel(
    float* __restrict__ Pbuf, const float* __restrict__ Qbuf, int N)
{
    const int idx = blockIdx.x * 256 + threadIdx.x;
    float run = 0.f;
#pragma unroll
    for (int s = 0; s < SEG; s++) {
        const float p = Pbuf[(size_t)s * N + idx];
        const float q = Qbuf[(size_t)s * N + idx];
        Pbuf[(size_t)s * N + idx] = run;       // h_in for segment s
        run = fmaf(p, run, q);
    }
}

__global__ __launch_bounds__(256) void scan_pass3_kernel(
    float* xzdt,                      // (R,1024): dt -> gated y, z in 512..1023
    const float* __restrict__ xc,     // (R,512)
    const float* __restrict__ bc,     // (R,32): B=0..15, C=16..31
    const float* __restrict__ A_log,  // (512,16)
    const float* __restrict__ Dp,     // (512)
    const float* __restrict__ Hin,    // [SEG][nb*512*16]  (aliases Pbuf)
    int nb)
{
    const int tid = threadIdx.x;
    const int dl = tid >> 2, nq = tid & 3;
    const int s = blockIdx.x & (SEG - 1);
    const int g = (blockIdx.x >> 5) & 7;
    const int b = blockIdx.x >> 8;
    const int d = g * 64 + dl;

    float4 Av = *(const float4*)(A_log + d * 16 + nq * 4);
    const float A0 = -__expf(Av.x), A1 = -__expf(Av.y);
    const float A2 = -__expf(Av.z), A3 = -__expf(Av.w);
    const float Dd = Dp[d];

    const int N = nb * 512 * 16;
    const int idx = (b * 512 + d) * 16 + nq * 4;
    float4 h4 = *(const float4*)(Hin + (size_t)s * N + idx);
    float h0 = h4.x, h1 = h4.y, h2 = h4.z, h3 = h4.w;

    const size_t row0 = (size_t)b * L_SEQ + (size_t)s * TSEG;
    float* dtp = xzdt + row0 * 1024 + d;
    const float* zp = xzdt + row0 * 1024 + 512 + d;
    const float* xcp = xc + row0 * 512 + d;
    const float* bp  = bc + row0 * 32 + nq * 4;

#pragma unroll 4
    for (int t = 0; t < TSEG; t++) {
        const float dt = dtp[(size_t)t * 1024];
        const float xcv = xcp[(size_t)t * 512];
        const float zv  = zp[(size_t)t * 1024];
        const float4 Bv = *(const float4*)(bp + (size_t)t * 32);
        const float4 Cv = *(const float4*)(bp + (size_t)t * 32 + 16);
        const float dtxc = dt * xcv;
        const float e0 = __expf(A0 * dt), e1 = __expf(A1 * dt);
        const float e2 = __expf(A2 * dt), e3 = __expf(A3 * dt);
        h0 = fmaf(e0, h0, dtxc * Bv.x);
        h1 = fmaf(e1, h1, dtxc * Bv.y);
        h2 = fmaf(e2, h2, dtxc * Bv.z);
        h3 = fmaf(e3, h3, dtxc * Bv.w);
        float pv = h0 * Cv.x + h1 * Cv.y + h2 * Cv.z + h3 * Cv.w;
        pv += __shfl_xor(pv, 1, 4);
        pv += __shfl_xor(pv, 2, 4);
        if (nq == 0) {
            const float sig = 1.f / (1.f + __expf(-zv));
            dtp[(size_t)t * 1024] = (pv + xcv * Dd) * (zv * sig);
        }
    }
}

// ---------------------------------------------------------------------------
// LayerNorm over 256 cols, in-place safe; one wave per row, 4 rows per block
// ---------------------------------------------------------------------------
__global__ __launch_bounds__(256) void ln256_kernel(
    const float* __restrict__ in, const float* __restrict__ g,
    const float* __restrict__ b, float* __restrict__ out)
{
    int wave = threadIdx.x >> 6, lane = threadIdx.x & 63;
    size_t row = (size_t)blockIdx.x * 4 + wave;
    const float* p = in + row * 256 + lane * 4;
    float4 v = *(const float4*)p;
    float s = v.x + v.y + v.z + v.w;
    float sq = v.x * v.x + v.y * v.y + v.z * v.z + v.w * v.w;
#pragma unroll
    for (int o = 32; o; o >>= 1) {
        s += __shfl_xor(s, o, 64);
        sq += __shfl_xor(sq, o, 64);
    }
    float m = s * (1.f / 256.f);
    float var = sq * (1.f / 256.f) - m * m;
    float rs = 1.f / sqrtf(var + LN_EPS);
    float4 gg = *(const float4*)(g + lane * 4);
    float4 bb = *(const float4*)(b + lane * 4);
    float4 o4;
    o4.x = (v.x - m) * rs * gg.x + bb.x;
    o4.y = (v.y - m) * rs * gg.y + bb.y;
    o4.z = (v.z - m) * rs * gg.z + bb.z;
    o4.w = (v.w - m) * rs * gg.w + bb.w;
    *(float4*)(out + row * 256 + lane * 4) = o4;
}

// ---------------------------------------------------------------------------
// head: tick-LN -> fusion (gelu, LN, linear) -> classifier.  1 block / batch row
// ---------------------------------------------------------------------------
__device__ __forceinline__ float gelu_exact(float x) {
    return 0.5f * x * (1.f + erff(x * 0.70710678118654752f));
}

__global__ __launch_bounds__(256) void head_kernel(
    const float* __restrict__ h, const float* __restrict__ sent,
    const float* __restrict__ ta,
    const float* __restrict__ eng, const float* __restrict__ enb,
    const float* __restrict__ w1, const float* __restrict__ b1,
    const float* __restrict__ lng, const float* __restrict__ lnb,
    const float* __restrict__ w2, const float* __restrict__ b2,
    const float* __restrict__ cw1, const float* __restrict__ cb1,
    const float* __restrict__ cw2, const float* __restrict__ cb2,
    const float* __restrict__ cw3, const float* __restrict__ cb3,
    float* __restrict__ out)
{
    __shared__ __align__(16) float comb[1036];
    __shared__ __align__(16) float fbuf[256];
    __shared__ float rs_[4], rq_[4];
    const int r = blockIdx.x, tid = threadIdx.x;

    // ---- tick = LN(h[:, L-1]) ----
    float v = h[((size_t)r * L_SEQ + (L_SEQ - 1)) * 256 + tid];
    float s = v, sq = v * v;
#pragma unroll
    for (int o = 32; o; o >>= 1) { s += __shfl_xor(s, o, 64); sq += __shfl_xor(sq, o, 64); }
    if ((tid & 63) == 0) { rs_[tid >> 6] = s; rq_[tid >> 6] = sq; }
    __syncthreads();
    s = rs_[0] + rs_[1] + rs_[2] + rs_[3];
    sq = rq_[0] + rq_[1] + rq_[2] + rq_[3];
    float m = s * (1.f / 256.f);
    float var = sq * (1.f / 256.f) - m * m;
    float rstd = 1.f / sqrtf(var + LN_EPS);
    comb[tid] = (v - m) * rstd * eng[tid] + enb[tid];
    comb[256 + tid] = sent[(size_t)r * 768 + tid];
    comb[512 + tid] = sent[(size_t)r * 768 + 256 + tid];
    comb[768 + tid] = sent[(size_t)r * 768 + 512 + tid];
    if (tid < 12) comb[1024 + tid] = ta[(size_t)r * 12 + tid];
    __syncthreads();

    // ---- f1 = gelu(comb @ w1^T + b1) ----
    float acc = b1[tid];
    {
        const float* wr = w1 + (size_t)tid * 1036;
        for (int k = 0; k < 1036; k += 4) {
            float4 wv = *(const float4*)(wr + k);
            float4 cv = *(const float4*)(comb + k);
            acc += wv.x * cv.x + wv.y * cv.y + wv.z * cv.z + wv.w * cv.w;
        }
    }
    float f1 = gelu_exact(acc);

    // ---- LN(f1) ----
    s = f1; sq = f1 * f1;
#pragma unroll
    for (int o = 32; o; o >>= 1) { s += __shfl_xor(s, o, 64); sq += __shfl_xor(sq, o, 64); }
    if ((tid & 63) == 0) { rs_[tid >> 6] = s; rq_[tid >> 6] = sq; }
    __syncthreads();
    s = rs_[0] + rs_[1] + rs_[2] + rs_[3];
    sq = rq_[0] + rq_[1] + rq_[2] + rq_[3];
    m = s * (1.f / 256.f);
    var = sq * (1.f / 256.f) - m * m;
    rstd = 1.f / sqrtf(var + LN_EPS);
    fbuf[tid] = (f1 - m) * rstd * lng[tid] + lnb[tid];
    __syncthreads();

    // ---- f2 = fbuf @ w2^T + b2 ----
    acc = b2[tid];
    {
        const float* wr = w2 + (size_t)tid * 256;
        for (int k = 0; k < 256; k += 4) {
            float4 wv = *(const float4*)(wr + k);
            float4 cv = *(const float4*)(fbuf + k);
            acc += wv.x * cv.x + wv.y * cv.y + wv.z * cv.z + wv.w * cv.w;
        }
    }
    __syncthreads();
    comb[tid] = acc;     // f2 lives in comb[0..255]
    __syncthreads();

    // ---- c1 = gelu(f2 @ cw1^T + cb1), 128 ----
    if (tid < 128) {
        float a = cb1[tid];
        const float* wr = cw1 + (size_t)tid * 256;
        for (int k = 0; k < 256; k += 4) {
            float4 wv = *(const float4*)(wr + k);
            float4 cv = *(const float4*)(comb + k);
            a += wv.x * cv.x + wv.y * cv.y + wv.z * cv.z + wv.w * cv.w;
        }
        fbuf[tid] = gelu_exact(a);
    }
    __syncthreads();

    // ---- c2 = gelu(c1 @ cw2^T + cb2), 64 ----
    float c2v = 0.f;
    if (tid < 64) {
        float a = cb2[tid];
        const float* wr = cw2 + (size_t)tid * 128;
        for (int k = 0; k < 128; k += 4) {
            float4 wv = *(const float4*)(wr + k);
            float4 cv = *(const float4*)(fbuf + k);
            a += wv.x * cv.x + wv.y * cv.y + wv.z * cv.z + wv.w * cv.w;
        }
        c2v = gelu_exact(a);
    }
    __syncthreads();
    if (tid < 64) comb[tid] = c2v;
    __syncthreads();

    // ---- logits ----
    if (tid < 3) {
        float a = cb3[tid];
        const float* wr = cw3 + (size_t)tid * 64;
        for (int k = 0; k < 64; k++) a += wr[k] * comb[k];
        out[(size_t)r * 3 + tid] = a;
    }
}

// ---------------------------------------------------------------------------
extern "C" void kernel_launch(void* const* d_in, const int* in_sizes, int n_in,
                              void* d_out, int out_size, void* d_ws, size_t ws_size,
                              hipStream_t stream) {
    const float* x    = (const float*)d_in[0];
    const float* sent = (const float*)d_in[1];
    const float* ta   = (const float*)d_in[2];
    const float* ipw  = (const float*)d_in[3];
    const float* ipb  = (const float*)d_in[4];
    const float* inw  = (const float*)d_in[5];
    const float* cw   = (const float*)d_in[6];
    const float* cb   = (const float*)d_in[7];
    const float* xpw  = (const float*)d_in[8];
    const float* dtw  = (const float*)d_in[9];
    const float* dtb  = (const float*)d_in[10];
    const float* alog = (const float*)d_in[11];
    const float* Dp   = (const float*)d_in[12];
    const float* opw  = (const float*)d_in[13];
    const float* lng  = (const float*)d_in[14];
    const float* lnb  = (const float*)d_in[15];
    const float* eng  = (const float*)d_in[16];
    const float* enb  = (const float*)d_in[17];
    const float* fw1  = (const float*)d_in[18];
    const float* fb1  = (const float*)d_in[19];
    const float* flg  = (const float*)d_in[20];
    const float* flb  = (const float*)d_in[21];
    const float* fw2  = (const float*)d_in[22];
    const float* fb2  = (const float*)d_in[23];
    const float* cw1  = (const float*)d_in[24];
    const float* cb1  = (const float*)d_in[25];
    const float* cw2  = (const float*)d_in[26];
    const float* cb2  = (const float*)d_in[27];
    const float* cw3  = (const float*)d_in[28];
    const float* cb3  = (const float*)d_in[29];
    float* out = (float*)d_out;

    // --- split-bf16 weight buffers.  elements (hi/lo each):
    //     in 4*262144, dt 4*262144, op 4*131072, xp 4*16384
    unsigned short* wbf = (unsigned short*)d_ws;
    const size_t OFF_IN_HI = 0,       OFF_IN_LO = 1048576;
    const size_t OFF_DT_HI = 2097152, OFF_DT_LO = 3145728;
    const size_t OFF_OP_HI = 4194304, OFF_OP_LO = 4718592;
    const size_t OFF_XP_HI = 5242880, OFF_XP_LO = 5308416;
    const size_t WBF_TOTAL = 5373952;            // bf16 elems = 10.75 MB
    float* fbase = (float*)(wbf + WBF_TOTAL);

    // --- workspace: weights + h (BL*256) + chunk temporaries:
    //     xz R*1024 + xc R*512 + bc R*32 = R*1568
    //   + P,Q: 2 * SEG * nb*512*16 = nb*524288 floats (Hin aliases Pbuf).
    int c = 1;
    while (c < 32 &&
           (WBF_TOTAL / 2 + (size_t)BL * 256 + ((size_t)BL / c) * 1568 +
            (size_t)(B_SZ / c) * 524288) * sizeof(float) > ws_size)
        c <<= 1;
    const size_t R = BL / c;        // rows per chunk (multiple of L_SEQ)
    const int nb = B_SZ / c;        // batches per chunk
    const int Nseg = nb * 512 * 16; // (b,d,n) states per chunk

    float* hbuf  = fbase;                      // BL*256 (persistent)
    float* xzbuf = hbuf + (size_t)BL * 256;    // R*1024
    float* xcbuf = xzbuf + R * 1024;           // R*512
    float* bcbuf = xcbuf + R * 512;            // R*32
    float* Pbuf  = bcbuf + R * 32;             // SEG*Nseg (also Hin)
    float* Qbuf  = Pbuf + (size_t)SEG * Nseg;  // SEG*Nseg

    // --- pre-split all weights to bf16 hi/lo (all 4 layers at once)
    convert_w_kernel<<<4096, 256, 0, stream>>>(inw, wbf + OFF_IN_HI, wbf + OFF_IN_LO, 1048576);
    convert_w_kernel<<<4096, 256, 0, stream>>>(dtw, wbf + OFF_DT_HI, wbf + OFF_DT_LO, 1048576);
    convert_w_kernel<<<2048, 256, 0, stream>>>(opw, wbf + OFF_OP_HI, wbf + OFF_OP_LO, 524288);
    convert_w_kernel<<<256, 256, 0, stream>>>(xpw, wbf + OFF_XP_HI, wbf + OFF_XP_LO, 65536);

    input_proj_kernel<<<BL, 256, 0, stream>>>(x, ipw, ipb, hbuf);

    for (int l = 0; l < 4; l++) {
        const float* cw_l  = cw  + (size_t)l * 512 * 4;
        const float* cb_l  = cb  + (size_t)l * 512;
        const float* dtb_l = dtb + (size_t)l * 512;
        const float* al_l  = alog + (size_t)l * 512 * 16;
        const float* Dp_l  = Dp  + (size_t)l * 512;
        const float* lng_l = lng + (size_t)l * 256;
        const float* lnb_l = lnb + (size_t)l * 256;
        const unsigned short* wih = wbf + OFF_IN_HI + (size_t)l * 262144;
        const unsigned short* wil = wbf + OFF_IN_LO + (size_t)l * 262144;
        const unsigned short* wdh = wbf + OFF_DT_HI + (size_t)l * 262144;
        const unsigned short* wdl = wbf + OFF_DT_LO + (size_t)l * 262144;
        const unsigned short* woh = wbf + OFF_OP_HI + (size_t)l * 131072;
        const unsigned short* wol = wbf + OFF_OP_LO + (size_t)l * 131072;
        const unsigned short* wxh = wbf + OFF_XP_HI + (size_t)l * 16384;
        const unsigned short* wxl = wbf + OFF_XP_LO + (size_t)l * 16384;

        for (int k = 0; k < c; k++) {
            float* hck = hbuf + (size_t)k * R * 256;

            // xz = h @ Wi^T            (R x 1024)
            gemm_bf16s<0><<<dim3(8, R / 128), 256, 0, stream>>>(
                hck, 256, wih, wil, nullptr, nullptr, xzbuf, 1024, (int)R, 1024, 256);
            // xc = silu(causal dwconv(xp) + cb), float4 over d
            conv_silu_kernel<<<(unsigned)(R / 2), 256, 0, stream>>>(
                xzbuf, cw_l, cb_l, xcbuf);
            // dt = softplus(xc @ Wdt^T + bdt)  -> xz cols 0..511 (xp is dead)
            gemm_bf16s<1><<<dim3(4, R / 128), 256, 0, stream>>>(
                xcbuf, 512, wdh, wdl, dtb_l, nullptr, xzbuf, 1024, (int)R, 512, 512);
            // bc = xc @ Wx^T            (R x 32), MFMA
            xproj_mfma_kernel<<<(unsigned)(R / 64), 256, 0, stream>>>(
                xcbuf, wxh, wxl, bcbuf);
            // segment-parallel selective scan + gate (in-place over dt half)
            scan_pass1_kernel<<<(unsigned)(nb * 8 * SEG), 256, 0, stream>>>(
                xzbuf, xcbuf, bcbuf, al_l, Pbuf, Qbuf, nb);
            scan_pass2_kernel<<<(unsigned)(Nseg / 256), 256, 0, stream>>>(
                Pbuf, Qbuf, Nseg);
            scan_pass3_kernel<<<(unsigned)(nb * 8 * SEG), 256, 0, stream>>>(
                xzbuf, xcbuf, bcbuf, al_l, Dp_l, Pbuf, nb);
            // h += y @ Wo^T  (in-place residual), then LN in-place
            gemm_bf16s<2><<<dim3(2, R / 128), 256, 0, stream>>>(
                xzbuf, 1024, woh, wol, nullptr, hck, hck, 256, (int)R, 256, 512);
            ln256_kernel<<<(unsigned)(R / 4), 256, 0, stream>>>(
                hck, lng_l, lnb_l, hck);
        }
    }

    head_kernel<<<32, 256, 0, stream>>>(hbuf, sent, ta, eng, enb,
                                        fw1, fb1, flg, flb, fw2, fb2,
                                        cw1, cb1, cw2, cb2, cw3, cb3, out);
}